// Round 11
// baseline (2307.936 us; speedup 1.0000x reference)
//
#include <hip/hip_runtime.h>
#include <hip/hip_bf16.h>

typedef unsigned short ushort_t;
typedef __attribute__((ext_vector_type(8))) short short8;   // 8 bf16 = 4 VGPRs
typedef __attribute__((ext_vector_type(4))) float f32x4;    // MFMA C/D

#define N_NODES 20000
#define N_EDGES 320000
#define F_NODE 64
#define F_EDGE 16
#define HID 300
#define HP 320          // padded hidden: K-dim and row stride of h/Sb/xW1b
#define NTILES 20       // wfrag n-tiles; tile 19 is pure pad (never used)
#define DEPTH 3
#define N_GRAPHS 128
#define KE2N 384        // e2n K: 64 (x) + 300 (S) + 20 pad; 12 chunks of 32

#define WFRAG_USHORT_PER_LAYER (10 * NTILES * 64 * 8)  // 102400 ushorts
#define W2FRAG_USHORT (12 * NTILES * 64 * 8)           // 122880 ushorts

__device__ __forceinline__ float bf2f(ushort_t u) {
    union { unsigned int i; float f; } v;
    v.i = ((unsigned int)u) << 16;
    return v.f;
}
__device__ __forceinline__ ushort_t f2bf(float f) {
    union { float f; unsigned int i; } v;
    v.f = f;
    unsigned int x = v.i;
    unsigned int r = x + 0x7fffu + ((x >> 16) & 1u);  // RNE
    return (ushort_t)(r >> 16);
}
__device__ __forceinline__ void bf2x(unsigned int w, float& lo, float& hi) {
    union { unsigned int i; float f; } a, b;
    a.i = w << 16; b.i = w & 0xffff0000u;
    lo = a.f; hi = b.f;
}
__device__ __forceinline__ unsigned int fpack(float lo, float hi) {
    return ((unsigned int)f2bf(lo)) | (((unsigned int)f2bf(hi)) << 16);
}

// ---------------- CSR build (col -> node adjacency) ----------------
__global__ __launch_bounds__(256) void csr_hist(
    const int* __restrict__ col, int* __restrict__ deg)
{
    int e = blockIdx.x * 256 + threadIdx.x;
    atomicAdd(&deg[col[e]], 1);
}

__global__ __launch_bounds__(256) void csr_scan(
    const int* __restrict__ deg, int* __restrict__ offsets,
    int* __restrict__ cursor)
{
    __shared__ int sums[256];
    const int t = threadIdx.x;
    const int CH = 79;  // 256*79 >= 20000
    int base = t * CH;
    int local = 0;
    for (int i = 0; i < CH; ++i) {
        int idx = base + i;
        if (idx < N_NODES) local += deg[idx];
    }
    sums[t] = local;
    __syncthreads();
    for (int off = 1; off < 256; off <<= 1) {
        int v = (t >= off) ? sums[t - off] : 0;
        __syncthreads();
        sums[t] += v;
        __syncthreads();
    }
    int run = (t > 0) ? sums[t - 1] : 0;
    for (int i = 0; i < CH; ++i) {
        int idx = base + i;
        if (idx < N_NODES) {
            offsets[idx] = run;
            cursor[idx] = run;
            run += deg[idx];
        }
    }
}

__global__ __launch_bounds__(256) void csr_fill(
    const int* __restrict__ col, int* __restrict__ cursor,
    int* __restrict__ eid)
{
    int e = blockIdx.x * 256 + threadIdx.x;
    int pos = atomicAdd(&cursor[col[e]], 1);
    eid[pos] = e;
}

// graph histogram over sorted batch
__global__ __launch_bounds__(256) void ghist(
    const int* __restrict__ batch, int* __restrict__ gdeg)
{
    int n = blockIdx.x * 256 + threadIdx.x;
    if (n < N_NODES) atomicAdd(&gdeg[batch[n]], 1);
}

__global__ __launch_bounds__(128) void gscan(
    const int* __restrict__ gdeg, int* __restrict__ goff)
{
    __shared__ int s[128];
    int t = threadIdx.x;
    int d = gdeg[t];
    s[t] = d;
    __syncthreads();
    for (int off = 1; off < 128; off <<= 1) {
        int v = (t >= off) ? s[t - off] : 0;
        __syncthreads();
        s[t] += v;
        __syncthreads();
    }
    goff[t] = s[t] - d;
    if (t == 127) goff[128] = s[127];
}

// ---------------- W pre-packs ----------------
__global__ __launch_bounds__(64) void wfrag_build(
    const float* __restrict__ W_convs, ushort_t* __restrict__ wfrag)
{
    const int c = blockIdx.x, t = blockIdx.y, l = blockIdx.z;
    const int lane = threadIdx.x;
    const int k0 = c * 32 + (lane >> 4) * 8;
    const int n  = t * 16 + (lane & 15);
    ushort_t* dst = wfrag + (size_t)l * WFRAG_USHORT_PER_LAYER
                  + ((size_t)(c * NTILES + t) * 64 + lane) * 8;
    const float* Wl = W_convs + (size_t)l * HID * HID;
    #pragma unroll
    for (int j = 0; j < 8; ++j) {
        int k = k0 + j;
        float v = (k < HID && n < HID) ? Wl[(long)k * HID + n] : 0.f;
        dst[j] = f2bf(v);
    }
}

__global__ __launch_bounds__(64) void wfrag2_build(
    const float* __restrict__ W_e2n, ushort_t* __restrict__ wfrag2)
{
    const int c = blockIdx.x, t = blockIdx.y;
    const int lane = threadIdx.x;
    const int k0 = c * 32 + (lane >> 4) * 8;
    const int n  = t * 16 + (lane & 15);
    ushort_t* dst = wfrag2 + ((size_t)(c * NTILES + t) * 64 + lane) * 8;
    #pragma unroll
    for (int j = 0; j < 8; ++j) {
        int k = k0 + j;
        float v = (k < F_NODE + HID && n < HID) ? W_e2n[(long)k * HID + n] : 0.f;
        dst[j] = f2bf(v);
    }
}

// W2 padded to [16][HP] fp32 (cols 300..319 zero)
__global__ __launch_bounds__(256) void w2pad_build(
    const float* __restrict__ W2, float* __restrict__ W2p)
{
    int i = blockIdx.x * 256 + threadIdx.x;  // 16*320 = 5120
    if (i >= 16 * HP) return;
    int j = i / HP, c = i % HP;
    W2p[i] = (c < HID) ? W2[(long)j * HID + c] : 0.f;
}

// ---------------- kernels ----------------

// K1: xW1b[n][c] = bf16(b_init[c] + x[n] @ W_init[0:64]);  stride HP, pad zero
__global__ __launch_bounds__(256) void node_init_gemm(
    const float* __restrict__ x, const float* __restrict__ W_init,
    const float* __restrict__ b_init, ushort_t* __restrict__ xW1b)
{
    __shared__ float xs[16 * 64];
    const int tid = threadIdx.x;
    const long n0 = (long)blockIdx.x * 16;
    for (int i = tid; i < 16 * 64; i += 256) xs[i] = x[n0 * 64 + i];
    __syncthreads();
    const int nl = tid >> 4, ct = tid & 15;
    for (int q = 0; q < 20; ++q) {
        int c = ct + 16 * q;
        if (c < HID) {
            float acc = b_init[c];
            #pragma unroll 8
            for (int k = 0; k < 64; ++k)
                acc = fmaf(xs[nl * 64 + k], W_init[(long)k * HID + c], acc);
            xW1b[(n0 + nl) * HP + c] = f2bf(acc);
        } else {
            xW1b[(n0 + nl) * HP + c] = 0;
        }
    }
}

// Fused conv layer — BARRIER-FREE, ZERO LDS.
// 64-edge block, 4 waves; wave w owns m-tile w (16 edges).  Lane (quad,m)
// computes its A-fragment (8 channels of edge e = e0+16w+m) in registers:
//   UPDATE:  af = relu(Sb[row[e]] - hW[e^1] + relu(xW1b[row[e]] + ea@W2p))
//            hW[e^1] = __shfl_xor(own hW, 1)   (e^1 is lane m^1, same quad)
//   !UPDATE: af = relu(xW1b[row[e]] + ea@W2p)  (layer 0; h not read)
// All 10 chunk-fragments kept in 40 VGPRs; n-tiles done in TWO passes
// (0..9 then 10..18; tile 19 = pure pad, skipped) so live acc = 40 AGPRs
// (R9 lesson: 76 AGPRs -> 3 waves/SIMD).  No barrier: chunks pipeline freely.
// In-place safe: wave reads only its own 16 h rows; all reads are
// data-consumed (MFMA inputs) before any store issues; C rows == own rows.
template<bool UPDATE>
__global__ __launch_bounds__(256) void fused_conv(
    ushort_t* h, const ushort_t* __restrict__ Sb,
    const ushort_t* __restrict__ xW1b, const float* __restrict__ edge_attr,
    const float* __restrict__ W2p, const int* __restrict__ row,
    const ushort_t* __restrict__ wfrag_l)
{
    const int tid = threadIdx.x;
    const int wave = tid >> 6, lane = tid & 63;
    const int quad = lane >> 4, m = lane & 15;
    const long e0 = (long)blockIdx.x * 64;
    const long e = e0 + wave * 16 + m;
    const int r = row[e];

    float ea[16];
    {
        const float4* eap = (const float4*)(edge_attr + e * 16);
        float4 v0 = eap[0], v1 = eap[1], v2 = eap[2], v3 = eap[3];
        ea[0]=v0.x; ea[1]=v0.y; ea[2]=v0.z; ea[3]=v0.w;
        ea[4]=v1.x; ea[5]=v1.y; ea[6]=v1.z; ea[7]=v1.w;
        ea[8]=v2.x; ea[9]=v2.y; ea[10]=v2.z; ea[11]=v2.w;
        ea[12]=v3.x; ea[13]=v3.y; ea[14]=v3.z; ea[15]=v3.w;
    }

    uint4 afrag[10];    // 40 VGPRs: A-fragments for all 10 K-chunks
    f32x4 acc[10];      // 40 AGPRs: n-tiles 0..9 (pass A)
    #pragma unroll
    for (int t = 0; t < 10; ++t) acc[t] = (f32x4){0.f, 0.f, 0.f, 0.f};

    // ---- pass A: build fragments + MFMA tiles 0..9 ----
    for (int c = 0; c < 10; ++c) {
        const int k0 = c * 32 + quad * 8;
        int4 xv = *(const int4*)(xW1b + (long)r * HP + k0);
        float h0t[8];
        bf2x((unsigned)xv.x, h0t[0], h0t[1]);
        bf2x((unsigned)xv.y, h0t[2], h0t[3]);
        bf2x((unsigned)xv.z, h0t[4], h0t[5]);
        bf2x((unsigned)xv.w, h0t[6], h0t[7]);
        #pragma unroll
        for (int j = 0; j < 16; ++j) {
            const float4 w0 = *(const float4*)(W2p + j * HP + k0);
            const float4 w1 = *(const float4*)(W2p + j * HP + k0 + 4);
            float a = ea[j];
            h0t[0] = fmaf(a, w0.x, h0t[0]); h0t[1] = fmaf(a, w0.y, h0t[1]);
            h0t[2] = fmaf(a, w0.z, h0t[2]); h0t[3] = fmaf(a, w0.w, h0t[3]);
            h0t[4] = fmaf(a, w1.x, h0t[4]); h0t[5] = fmaf(a, w1.y, h0t[5]);
            h0t[6] = fmaf(a, w1.z, h0t[6]); h0t[7] = fmaf(a, w1.w, h0t[7]);
        }
        float hn[8];
        if (UPDATE) {
            int4 wv = *(const int4*)(h + e * HP + k0);
            int4 sv = *(const int4*)(Sb + (long)r * HP + k0);
            int4 wr;
            wr.x = __shfl_xor(wv.x, 1); wr.y = __shfl_xor(wv.y, 1);
            wr.z = __shfl_xor(wv.z, 1); wr.w = __shfl_xor(wv.w, 1);
            float s[8], w[8];
            bf2x((unsigned)sv.x, s[0], s[1]); bf2x((unsigned)sv.y, s[2], s[3]);
            bf2x((unsigned)sv.z, s[4], s[5]); bf2x((unsigned)sv.w, s[6], s[7]);
            bf2x((unsigned)wr.x, w[0], w[1]); bf2x((unsigned)wr.y, w[2], w[3]);
            bf2x((unsigned)wr.z, w[4], w[5]); bf2x((unsigned)wr.w, w[6], w[7]);
            #pragma unroll
            for (int jj = 0; jj < 8; ++jj)
                hn[jj] = fmaxf(s[jj] - w[jj] + fmaxf(h0t[jj], 0.f), 0.f);
        } else {
            #pragma unroll
            for (int jj = 0; jj < 8; ++jj)
                hn[jj] = fmaxf(h0t[jj], 0.f);
        }
        uint4 af;
        af.x = fpack(hn[0], hn[1]); af.y = fpack(hn[2], hn[3]);
        af.z = fpack(hn[4], hn[5]); af.w = fpack(hn[6], hn[7]);
        afrag[c] = af;
        union { uint4 u4; short8 s8; } cv; cv.u4 = af;
        #pragma unroll
        for (int t = 0; t < 10; ++t) {
            short8 b = *(const short8*)(wfrag_l
                + ((size_t)(c * NTILES + t) * 64 + lane) * 8);
            acc[t] = __builtin_amdgcn_mfma_f32_16x16x32_bf16(
                cv.s8, b, acc[t], 0, 0, 0);
        }
    }
    // store tiles 0..9 (cols 0..159, all < 300); own rows only
    #pragma unroll
    for (int t = 0; t < 10; ++t) {
        int col = t * 16 + m;
        long rbase = (e0 + wave * 16 + quad * 4) * HP + col;
        #pragma unroll
        for (int r4 = 0; r4 < 4; ++r4)
            h[rbase + (long)r4 * HP] = f2bf(acc[t][r4]);
    }

    // ---- pass B: tiles 10..18 from register-cached fragments ----
    f32x4 acc2[9];
    #pragma unroll
    for (int t = 0; t < 9; ++t) acc2[t] = (f32x4){0.f, 0.f, 0.f, 0.f};
    for (int c = 0; c < 10; ++c) {
        union { uint4 u4; short8 s8; } cv; cv.u4 = afrag[c];
        #pragma unroll
        for (int t = 0; t < 9; ++t) {
            short8 b = *(const short8*)(wfrag_l
                + ((size_t)(c * NTILES + 10 + t) * 64 + lane) * 8);
            acc2[t] = __builtin_amdgcn_mfma_f32_16x16x32_bf16(
                cv.s8, b, acc2[t], 0, 0, 0);
        }
    }
    #pragma unroll
    for (int t = 0; t < 9; ++t) {
        int col = (10 + t) * 16 + m;
        if (col >= HID) continue;   // only t=8, m>=12
        long rbase = (e0 + wave * 16 + quad * 4) * HP + col;
        #pragma unroll
        for (int r4 = 0; r4 < 4; ++r4)
            h[rbase + (long)r4 * HP] = f2bf(acc2[t][r4]);
    }
}

// K4: Sb[n][:] = bf16( bias[:] + segsum );  stride HP, pad quads zeroed
__global__ __launch_bounds__(256) void gather_sum(
    const ushort_t* __restrict__ src, const int* __restrict__ offsets,
    const int* __restrict__ ends, const int* __restrict__ eid,
    const float* __restrict__ bias, ushort_t* __restrict__ Sb)
{
    long idx = (long)blockIdx.x * 256 + threadIdx.x;
    if (idx >= (long)N_NODES * 80) return;
    int n = (int)(idx / 80);
    int g = (int)(idx % 80);
    if (g >= 75) {
        ushort4 z = {0, 0, 0, 0};
        *(ushort4*)&Sb[(long)n * HP + 4 * g] = z;
        return;
    }
    int beg = offsets[n], end = ends[n];
    float a0 = 0.f, a1 = 0.f, a2 = 0.f, a3 = 0.f;
    float b0 = 0.f, b1 = 0.f, b2 = 0.f, b3 = 0.f;
    int j = beg;
    for (; j + 1 < end; j += 2) {
        int e0i = eid[j], e1i = eid[j + 1];
        ushort4 v0 = ((const ushort4*)src)[(long)e0i * (HP / 4) + g];
        ushort4 v1 = ((const ushort4*)src)[(long)e1i * (HP / 4) + g];
        a0 += bf2f(v0.x); a1 += bf2f(v0.y); a2 += bf2f(v0.z); a3 += bf2f(v0.w);
        b0 += bf2f(v1.x); b1 += bf2f(v1.y); b2 += bf2f(v1.z); b3 += bf2f(v1.w);
    }
    if (j < end) {
        int e0i = eid[j];
        ushort4 v0 = ((const ushort4*)src)[(long)e0i * (HP / 4) + g];
        a0 += bf2f(v0.x); a1 += bf2f(v0.y); a2 += bf2f(v0.z); a3 += bf2f(v0.w);
    }
    float4 bv = *(const float4*)&bias[4 * g];
    ushort4 o;
    o.x = f2bf(a0 + b0 + bv.x); o.y = f2bf(a1 + b1 + bv.y);
    o.z = f2bf(a2 + b2 + bv.z); o.w = f2bf(a3 + b3 + bv.w);
    *(ushort4*)&Sb[(long)n * HP + 4 * g] = o;
}

// K4b: final gather -> bf16 directly into Ab cols 64..363 (stride KE2N, no bias)
__global__ __launch_bounds__(256) void gather_ab(
    const ushort_t* __restrict__ src, const int* __restrict__ offsets,
    const int* __restrict__ ends, const int* __restrict__ eid,
    ushort_t* __restrict__ Ab)
{
    long idx = (long)blockIdx.x * 256 + threadIdx.x;
    if (idx >= (long)N_NODES * 75) return;
    int n = (int)(idx / 75);
    int g = (int)(idx % 75);
    int beg = offsets[n], end = ends[n];
    float a0 = 0.f, a1 = 0.f, a2 = 0.f, a3 = 0.f;
    float b0 = 0.f, b1 = 0.f, b2 = 0.f, b3 = 0.f;
    int j = beg;
    for (; j + 1 < end; j += 2) {
        int e0i = eid[j], e1i = eid[j + 1];
        ushort4 v0 = ((const ushort4*)src)[(long)e0i * (HP / 4) + g];
        ushort4 v1 = ((const ushort4*)src)[(long)e1i * (HP / 4) + g];
        a0 += bf2f(v0.x); a1 += bf2f(v0.y); a2 += bf2f(v0.z); a3 += bf2f(v0.w);
        b0 += bf2f(v1.x); b1 += bf2f(v1.y); b2 += bf2f(v1.z); b3 += bf2f(v1.w);
    }
    if (j < end) {
        int e0i = eid[j];
        ushort4 v0 = ((const ushort4*)src)[(long)e0i * (HP / 4) + g];
        a0 += bf2f(v0.x); a1 += bf2f(v0.y); a2 += bf2f(v0.z); a3 += bf2f(v0.w);
    }
    ushort4 o;
    o.x = f2bf(a0 + b0); o.y = f2bf(a1 + b1);
    o.z = f2bf(a2 + b2); o.w = f2bf(a3 + b3);
    *(ushort4*)&Ab[(long)n * KE2N + 64 + 4 * g] = o;
}

// fill Ab cols 0..63 from x (bf16) and zero cols 364..383
__global__ __launch_bounds__(256) void x_fill(
    const float* __restrict__ x, ushort_t* __restrict__ Ab)
{
    long idx = (long)blockIdx.x * 256 + threadIdx.x;  // over N_NODES*21
    if (idx >= (long)N_NODES * 21) return;
    int n = (int)(idx / 21);
    int q = (int)(idx % 21);
    ushort4 o;
    if (q < 16) {
        float4 v = *(const float4*)&x[(long)n * 64 + 4 * q];
        o.x = f2bf(v.x); o.y = f2bf(v.y); o.z = f2bf(v.z); o.w = f2bf(v.w);
        *(ushort4*)&Ab[(long)n * KE2N + 4 * q] = o;
    } else {
        o.x = 0; o.y = 0; o.z = 0; o.w = 0;
        *(ushort4*)&Ab[(long)n * KE2N + 364 + 4 * (q - 16)] = o;
    }
}

// K7: hn = relu(Ab @ W_e2n + b)  via MFMA; no LDS, no barriers (C != A).
__global__ __launch_bounds__(256) void e2n_mfma(
    const ushort_t* __restrict__ Ab, const ushort_t* __restrict__ wfrag2,
    const float* __restrict__ b_e2n, float* __restrict__ hn)
{
    const int tid = threadIdx.x;
    const int wave = tid >> 6, lane = tid & 63;
    const int quad = lane >> 4, m = lane & 15;
    const long n0 = (long)blockIdx.x * 64;
    const int nt0 = wave * 5;

    f32x4 acc[5][4];
    #pragma unroll
    for (int t = 0; t < 5; ++t)
        #pragma unroll
        for (int mt = 0; mt < 4; ++mt)
            acc[t][mt] = (f32x4){0.f, 0.f, 0.f, 0.f};

    for (int c = 0; c < 12; ++c) {
        short8 a[4];
        #pragma unroll
        for (int mt = 0; mt < 4; ++mt) {
            long r = n0 + mt * 16 + m;
            if (r > N_NODES - 1) r = N_NODES - 1;  // clamp (stores masked)
            a[mt] = *(const short8*)(Ab + r * KE2N + c * 32 + quad * 8);
        }
        #pragma unroll
        for (int t = 0; t < 5; ++t) {
            short8 b = *(const short8*)(wfrag2
                + ((size_t)(c * NTILES + nt0 + t) * 64 + lane) * 8);
            #pragma unroll
            for (int mt = 0; mt < 4; ++mt)
                acc[t][mt] = __builtin_amdgcn_mfma_f32_16x16x32_bf16(
                    a[mt], b, acc[t][mt], 0, 0, 0);
        }
    }

    #pragma unroll
    for (int t = 0; t < 5; ++t) {
        int col = (nt0 + t) * 16 + m;
        if (col >= HID) continue;
        float bias = b_e2n[col];
        #pragma unroll
        for (int mt = 0; mt < 4; ++mt) {
            long rw = n0 + mt * 16 + quad * 4;
            #pragma unroll
            for (int r = 0; r < 4; ++r) {
                long rowi = rw + r;
                if (rowi < N_NODES)
                    hn[rowi * HP + col] = fmaxf(acc[t][mt][r] + bias, 0.f);
            }
        }
    }
}

// K7b: pooled[g][c] = sum of hn rows in [goff[g], goff[g+1])  (sorted batch)
__global__ __launch_bounds__(256) void pool_graph(
    const float* __restrict__ hn, const int* __restrict__ goff,
    float* __restrict__ pooled)
{
    int g = blockIdx.x;
    int beg = goff[g], end = goff[g + 1];
    for (int c = threadIdx.x; c < HID; c += 256) {
        float acc = 0.f;
        for (int n = beg; n < end; ++n)
            acc += hn[(long)n * HP + c];
        pooled[(long)g * HID + c] = acc;
    }
}

// K5 (final layer only): standalone pair-threaded in-place edge update.
__global__ __launch_bounds__(256) void edge_update_pairs(
    ushort_t* h, const ushort_t* __restrict__ Sb,
    const ushort_t* __restrict__ xW1b, const float* __restrict__ edge_attr,
    const float* __restrict__ W2, const int* __restrict__ row)
{
    __shared__ float eas[64 * 16];
    __shared__ int rows[64];
    const int tid = threadIdx.x;
    const long e0 = (long)blockIdx.x * 64;

    for (int i = tid; i < 64 * 16; i += 256)
        eas[i] = edge_attr[e0 * 16 + i];
    if (tid < 64) rows[tid] = row[e0 + tid];
    __syncthreads();

    for (int i = tid; i < 32 * 75; i += 256) {
        int p = i / 75, g = i % 75;
        int c0 = 4 * g;
        int la = 2 * p, lb = 2 * p + 1;
        long Ea = e0 + la, Eb = e0 + lb;
        int ra = rows[la], rb = rows[lb];

        ushort4 wa = *(const ushort4*)&h[Ea * HP + c0];
        ushort4 wb = *(const ushort4*)&h[Eb * HP + c0];
        ushort4 sa = *(const ushort4*)&Sb[(long)ra * HP + c0];
        ushort4 sb = *(const ushort4*)&Sb[(long)rb * HP + c0];
        ushort4 xa = *(const ushort4*)&xW1b[(long)ra * HP + c0];
        ushort4 xb = *(const ushort4*)&xW1b[(long)rb * HP + c0];

        float h0a[4] = {bf2f(xa.x), bf2f(xa.y), bf2f(xa.z), bf2f(xa.w)};
        float h0b[4] = {bf2f(xb.x), bf2f(xb.y), bf2f(xb.z), bf2f(xb.w)};
        #pragma unroll
        for (int k = 0; k < 16; ++k) {
            float aa = eas[la * 16 + k];
            float ab = eas[lb * 16 + k];
            const float4 w0 = *(const float4*)&W2[(long)k * HID + c0];
            h0a[0] = fmaf(aa, w0.x, h0a[0]); h0b[0] = fmaf(ab, w0.x, h0b[0]);
            h0a[1] = fmaf(aa, w0.y, h0a[1]); h0b[1] = fmaf(ab, w0.y, h0b[1]);
            h0a[2] = fmaf(aa, w0.z, h0a[2]); h0b[2] = fmaf(ab, w0.z, h0b[2]);
            h0a[3] = fmaf(aa, w0.w, h0a[3]); h0b[3] = fmaf(ab, w0.w, h0b[3]);
        }
        ushort4 ova, ovb;
        ova.x = f2bf(fmaxf(bf2f(sa.x) - bf2f(wb.x) + fmaxf(h0a[0], 0.f), 0.f));
        ova.y = f2bf(fmaxf(bf2f(sa.y) - bf2f(wb.y) + fmaxf(h0a[1], 0.f), 0.f));
        ova.z = f2bf(fmaxf(bf2f(sa.z) - bf2f(wb.z) + fmaxf(h0a[2], 0.f), 0.f));
        ova.w = f2bf(fmaxf(bf2f(sa.w) - bf2f(wb.w) + fmaxf(h0a[3], 0.f), 0.f));
        ovb.x = f2bf(fmaxf(bf2f(sb.x) - bf2f(wa.x) + fmaxf(h0b[0], 0.f), 0.f));
        ovb.y = f2bf(fmaxf(bf2f(sb.y) - bf2f(wa.y) + fmaxf(h0b[1], 0.f), 0.f));
        ovb.z = f2bf(fmaxf(bf2f(sb.z) - bf2f(wa.z) + fmaxf(h0b[2], 0.f), 0.f));
        ovb.w = f2bf(fmaxf(bf2f(sb.w) - bf2f(wa.w) + fmaxf(h0b[3], 0.f), 0.f));
        ((ushort4*)h)[Ea * (HP / 4) + g] = ova;
        ((ushort4*)h)[Eb * (HP / 4) + g] = ovb;
    }
}

// K8: out[g] = pooled[g] @ W_ffn + b_ffn
__global__ __launch_bounds__(64) void ffn_out(
    const float* __restrict__ pooled, const float* __restrict__ W_ffn,
    const float* __restrict__ b_ffn, float* __restrict__ out)
{
    int g = blockIdx.x;
    int lane = threadIdx.x;
    float s = 0.f;
    for (int c = lane; c < HID; c += 64)
        s += pooled[(long)g * HID + c] * W_ffn[c];
    #pragma unroll
    for (int off = 32; off > 0; off >>= 1)
        s += __shfl_down(s, off, 64);
    if (lane == 0) out[g] = s + b_ffn[0];
}

extern "C" void kernel_launch(void* const* d_in, const int* in_sizes, int n_in,
                              void* d_out, int out_size, void* d_ws, size_t ws_size,
                              hipStream_t stream) {
    const float* x         = (const float*)d_in[0];
    const float* edge_attr = (const float*)d_in[1];
    const int*   edge_index= (const int*)d_in[2];
    const int*   batch     = (const int*)d_in[3];
    const float* W_init    = (const float*)d_in[4];
    const float* b_init    = (const float*)d_in[5];
    const float* W_convs   = (const float*)d_in[6];
    const float* b_convs   = (const float*)d_in[7];
    const float* W_e2n     = (const float*)d_in[8];
    const float* b_e2n     = (const float*)d_in[9];
    const float* W_ffn     = (const float*)d_in[10];
    const float* b_ffn     = (const float*)d_in[11];
    float* out = (float*)d_out;

    const int* row = edge_index;
    const int* col = edge_index + N_EDGES;
    const float* W2 = W_init + (size_t)F_NODE * HID;

    // Workspace (~249 MB): h 204.8M | Sb 12.8M | xW1b 12.8M | Ab 15.36M
    // | pooled 0.15M | cursor/offsets 0.16M | eid 1.28M | wfrag 0.61M
    // | wfrag2 0.25M | W2p 20K
    const size_t need = (size_t)N_EDGES * HP * 2
                      + (size_t)N_NODES * HP * 2 * 2           // Sb + xW1b
                      + (size_t)N_NODES * KE2N * 2             // Ab
                      + (size_t)N_GRAPHS * HID * 4
                      + (size_t)N_NODES * 4 * 2 + (size_t)N_EDGES * 4
                      + (size_t)DEPTH * WFRAG_USHORT_PER_LAYER * 2
                      + (size_t)W2FRAG_USHORT * 2
                      + (size_t)16 * HP * 4
                      + (size_t)(N_GRAPHS + 1 + N_GRAPHS) * 4 + 32768;
    if (ws_size < need) return;  // clean absmax fail, not a crash

    char* p = (char*)d_ws;
    auto take = [&](size_t bytes) {
        char* q = p;
        p += (bytes + 255) & ~(size_t)255;
        return q;
    };
    ushort_t* h       = (ushort_t*)take((size_t)N_EDGES * HP * 2);
    ushort_t* Sb      = (ushort_t*)take((size_t)N_NODES * HP * 2);
    ushort_t* xW1b    = (ushort_t*)take((size_t)N_NODES * HP * 2);
    ushort_t* Ab      = (ushort_t*)take((size_t)N_NODES * KE2N * 2);
    float*    pooled  = (float*)take((size_t)N_GRAPHS * HID * 4);
    int*      cursor  = (int*)take((size_t)N_NODES * 4);
    int*      offsets = (int*)take((size_t)N_NODES * 4);
    int*      eid     = (int*)take((size_t)N_EDGES * 4);
    ushort_t* wfrag   = (ushort_t*)take((size_t)DEPTH * WFRAG_USHORT_PER_LAYER * 2);
    ushort_t* wfrag2  = (ushort_t*)take((size_t)W2FRAG_USHORT * 2);
    float*    W2p     = (float*)take((size_t)16 * HP * 4);
    int*      gdeg    = (int*)take((size_t)N_GRAPHS * 4);
    int*      goff    = (int*)take((size_t)(N_GRAPHS + 1) * 4);

    float* hn = (float*)h;  // 25.6 MB <= 204.8 MB; h dead after gather_ab

    // CSR build (edges by col; graphs by sorted batch)
    hipMemsetAsync(cursor, 0, (size_t)N_NODES * 4, stream);
    hipMemsetAsync(gdeg, 0, (size_t)N_GRAPHS * 4, stream);
    csr_hist<<<N_EDGES / 256, 256, 0, stream>>>(col, cursor);
    csr_scan<<<1, 256, 0, stream>>>(cursor, offsets, cursor);
    csr_fill<<<N_EDGES / 256, 256, 0, stream>>>(col, cursor, eid);
    ghist<<<(N_NODES + 255) / 256, 256, 0, stream>>>(batch, gdeg);
    gscan<<<1, 128, 0, stream>>>(gdeg, goff);

    // W pre-packs
    wfrag_build<<<dim3(10, NTILES, DEPTH), 64, 0, stream>>>(W_convs, wfrag);
    wfrag2_build<<<dim3(12, NTILES, 1), 64, 0, stream>>>(W_e2n, wfrag2);
    w2pad_build<<<(16 * HP + 255) / 256, 256, 0, stream>>>(W2, W2p);

    node_init_gemm<<<N_NODES / 16, 256, 0, stream>>>(x, W_init, b_init, xW1b);

    const int GS_GRID = ((N_NODES * 80) + 255) / 256;
    const int GA_GRID = ((N_NODES * 75) + 255) / 256;

    // layer 0: h0 built in registers, gemm -> hW_0
    fused_conv<false><<<N_EDGES / 64, 256, 0, stream>>>(
        h, Sb, xW1b, edge_attr, W2p, row, wfrag);
    gather_sum<<<GS_GRID, 256, 0, stream>>>(
        h, offsets, cursor, eid, b_convs + 0 * HID, Sb);
    // layers 1,2: update fused with gemm
    fused_conv<true><<<N_EDGES / 64, 256, 0, stream>>>(
        h, Sb, xW1b, edge_attr, W2p, row, wfrag + 1 * (size_t)WFRAG_USHORT_PER_LAYER);
    gather_sum<<<GS_GRID, 256, 0, stream>>>(
        h, offsets, cursor, eid, b_convs + 1 * HID, Sb);
    fused_conv<true><<<N_EDGES / 64, 256, 0, stream>>>(
        h, Sb, xW1b, edge_attr, W2p, row, wfrag + 2 * (size_t)WFRAG_USHORT_PER_LAYER);
    gather_sum<<<GS_GRID, 256, 0, stream>>>(
        h, offsets, cursor, eid, b_convs + 2 * HID, Sb);
    // final standalone update -> h_3
    edge_update_pairs<<<N_EDGES / 64, 256, 0, stream>>>(
        h, Sb, xW1b, edge_attr, W2, row);

    // ---- e2n path ----
    x_fill<<<((N_NODES * 21) + 255) / 256, 256, 0, stream>>>(x, Ab);
    gather_ab<<<GA_GRID, 256, 0, stream>>>(h, offsets, cursor, eid, Ab);
    e2n_mfma<<<(N_NODES + 63) / 64, 256, 0, stream>>>(Ab, wfrag2, b_e2n, hn);
    pool_graph<<<N_GRAPHS, 256, 0, stream>>>(hn, goff, pooled);
    ffn_out<<<N_GRAPHS, 64, 0, stream>>>(pooled, W_ffn, b_ffn, out);
}

// Round 12
// 1564.973 us; speedup vs baseline: 1.4747x; 1.4747x over previous
//
#include <hip/hip_runtime.h>
#include <hip/hip_bf16.h>

typedef unsigned short ushort_t;
typedef __attribute__((ext_vector_type(8))) short short8;   // 8 bf16 = 4 VGPRs
typedef __attribute__((ext_vector_type(4))) float f32x4;    // MFMA C/D

#define N_NODES 20000
#define N_EDGES 320000
#define F_NODE 64
#define F_EDGE 16
#define HID 300
#define HP 320          // padded hidden: K-dim and row stride of h/h0buf
#define NTILES 20       // wfrag n-tiles; tile 19 pure pad
#define DEPTH 3
#define N_GRAPHS 128
#define KE2N 384        // e2n K: 64 (x) + 300 (S) + 20 pad
#define ATS 328         // LDS A-tile row stride (ushorts)

#define WFRAG_USHORT_PER_LAYER (10 * NTILES * 64 * 8)  // 102400 ushorts
#define W2FRAG_USHORT (12 * NTILES * 64 * 8)           // 122880 ushorts

__device__ __forceinline__ float bf2f(ushort_t u) {
    union { unsigned int i; float f; } v;
    v.i = ((unsigned int)u) << 16;
    return v.f;
}
__device__ __forceinline__ ushort_t f2bf(float f) {
    union { float f; unsigned int i; } v;
    v.f = f;
    unsigned int x = v.i;
    unsigned int r = x + 0x7fffu + ((x >> 16) & 1u);  // RNE
    return (ushort_t)(r >> 16);
}

// ---------------- CSR build ----------------
__global__ __launch_bounds__(256) void csr_hist(
    const int* __restrict__ col, int* __restrict__ deg)
{
    int e = blockIdx.x * 256 + threadIdx.x;
    atomicAdd(&deg[col[e]], 1);
}

__global__ __launch_bounds__(256) void csr_scan(
    const int* __restrict__ deg, int* __restrict__ offsets,
    int* __restrict__ cursor)
{
    __shared__ int sums[256];
    const int t = threadIdx.x;
    const int CH = 79;
    int base = t * CH;
    int local = 0;
    for (int i = 0; i < CH; ++i) {
        int idx = base + i;
        if (idx < N_NODES) local += deg[idx];
    }
    sums[t] = local;
    __syncthreads();
    for (int off = 1; off < 256; off <<= 1) {
        int v = (t >= off) ? sums[t - off] : 0;
        __syncthreads();
        sums[t] += v;
        __syncthreads();
    }
    int run = (t > 0) ? sums[t - 1] : 0;
    for (int i = 0; i < CH; ++i) {
        int idx = base + i;
        if (idx < N_NODES) {
            offsets[idx] = run;
            cursor[idx] = run;
            run += deg[idx];
        }
    }
}

__global__ __launch_bounds__(256) void csr_fill(
    const int* __restrict__ col, int* __restrict__ cursor,
    int* __restrict__ eid)
{
    int e = blockIdx.x * 256 + threadIdx.x;
    int pos = atomicAdd(&cursor[col[e]], 1);
    eid[pos] = e;
}

__global__ __launch_bounds__(256) void ghist(
    const int* __restrict__ batch, int* __restrict__ gdeg)
{
    int n = blockIdx.x * 256 + threadIdx.x;
    if (n < N_NODES) atomicAdd(&gdeg[batch[n]], 1);
}

__global__ __launch_bounds__(128) void gscan(
    const int* __restrict__ gdeg, int* __restrict__ goff)
{
    __shared__ int s[128];
    int t = threadIdx.x;
    int d = gdeg[t];
    s[t] = d;
    __syncthreads();
    for (int off = 1; off < 128; off <<= 1) {
        int v = (t >= off) ? s[t - off] : 0;
        __syncthreads();
        s[t] += v;
        __syncthreads();
    }
    goff[t] = s[t] - d;
    if (t == 127) goff[128] = s[127];
}

// ---------------- W fragment pre-pack ----------------
__global__ __launch_bounds__(64) void wfrag_build(
    const float* __restrict__ W_convs, ushort_t* __restrict__ wfrag)
{
    const int c = blockIdx.x, t = blockIdx.y, l = blockIdx.z;
    const int lane = threadIdx.x;
    const int k0 = c * 32 + (lane >> 4) * 8;
    const int n  = t * 16 + (lane & 15);
    ushort_t* dst = wfrag + (size_t)l * WFRAG_USHORT_PER_LAYER
                  + ((size_t)(c * NTILES + t) * 64 + lane) * 8;
    const float* Wl = W_convs + (size_t)l * HID * HID;
    #pragma unroll
    for (int j = 0; j < 8; ++j) {
        int k = k0 + j;
        float v = (k < HID && n < HID) ? Wl[(long)k * HID + n] : 0.f;
        dst[j] = f2bf(v);
    }
}

__global__ __launch_bounds__(64) void wfrag2_build(
    const float* __restrict__ W_e2n, ushort_t* __restrict__ wfrag2)
{
    const int c = blockIdx.x, t = blockIdx.y;
    const int lane = threadIdx.x;
    const int k0 = c * 32 + (lane >> 4) * 8;
    const int n  = t * 16 + (lane & 15);
    ushort_t* dst = wfrag2 + ((size_t)(c * NTILES + t) * 64 + lane) * 8;
    #pragma unroll
    for (int j = 0; j < 8; ++j) {
        int k = k0 + j;
        float v = (k < F_NODE + HID && n < HID) ? W_e2n[(long)k * HID + n] : 0.f;
        dst[j] = f2bf(v);
    }
}

// ---------------- kernels ----------------

// K1: xW1b[n][c] = bf16(b_init[c] + x[n] @ W_init[0:64]);  stride HID
__global__ __launch_bounds__(256) void node_init_gemm(
    const float* __restrict__ x, const float* __restrict__ W_init,
    const float* __restrict__ b_init, ushort_t* __restrict__ xW1b)
{
    __shared__ float xs[16 * 64];
    const int tid = threadIdx.x;
    const long n0 = (long)blockIdx.x * 16;
    for (int i = tid; i < 16 * 64; i += 256) xs[i] = x[n0 * 64 + i];
    __syncthreads();
    const int nl = tid >> 4, ct = tid & 15;
    for (int q = 0; q < 19; ++q) {
        int c = ct + 16 * q;
        if (c < HID) {
            float acc = b_init[c];
            #pragma unroll 8
            for (int k = 0; k < 64; ++k)
                acc = fmaf(xs[nl * 64 + k], W_init[(long)k * HID + c], acc);
            xW1b[(n0 + nl) * HID + c] = f2bf(acc);
        }
    }
}

// h0_build (big path): h0buf[e][c] = relu(xW1b[row[e]][c] + ea[e]@W2);
// stride HP, cols 300..319 zero.  Computed ONCE (was recomputed 4x/call).
__global__ __launch_bounds__(256) void h0_build(
    const float* __restrict__ edge_attr, const int* __restrict__ row,
    const ushort_t* __restrict__ xW1b, const float* __restrict__ W_init,
    ushort_t* __restrict__ h0buf)
{
    __shared__ float W2s[16 * HID];
    __shared__ float eas[16 * 16];
    const int tid = threadIdx.x;
    const long e0 = (long)blockIdx.x * 16;
    for (int i = tid; i < 16 * HID; i += 256) {
        int k = i / HID, c = i % HID;
        W2s[i] = W_init[(long)(64 + k) * HID + c];
    }
    eas[tid] = edge_attr[e0 * 16 + tid];
    __syncthreads();
    const int el = tid >> 4, ct = tid & 15;
    const long e = e0 + el;
    const int r = row[e];
    float ea[16];
    #pragma unroll
    for (int k = 0; k < 16; ++k) ea[k] = eas[el * 16 + k];
    for (int q = 0; q < 20; ++q) {
        int c = ct + 16 * q;
        if (c < HID) {
            float acc = bf2f(xW1b[(long)r * HID + c]);
            #pragma unroll
            for (int k = 0; k < 16; ++k)
                acc = fmaf(ea[k], W2s[k * HID + c], acc);
            h0buf[e * HP + c] = f2bf(fmaxf(acc, 0.f));
        } else {
            h0buf[e * HP + c] = 0;
        }
    }
}

// gemm0 (big path): h = h0buf @ W0.  32-edge block, no LDS, NO barrier (A!=C).
__global__ __launch_bounds__(256) void gemm0_mfma(
    const ushort_t* __restrict__ A, const ushort_t* __restrict__ wfrag_l,
    ushort_t* __restrict__ C)
{
    const int tid = threadIdx.x;
    const int wave = tid >> 6, lane = tid & 63;
    const int quad = lane >> 4, m = lane & 15;
    const long e0 = (long)blockIdx.x * 32;
    const int nt0 = wave * 5;

    f32x4 acc[5][2];
    #pragma unroll
    for (int t = 0; t < 5; ++t)
        #pragma unroll
        for (int mt = 0; mt < 2; ++mt)
            acc[t][mt] = (f32x4){0.f, 0.f, 0.f, 0.f};

    for (int c = 0; c < 10; ++c) {
        short8 a0 = *(const short8*)(A + (e0 + m) * HP + c * 32 + quad * 8);
        short8 a1 = *(const short8*)(A + (e0 + 16 + m) * HP + c * 32 + quad * 8);
        #pragma unroll
        for (int t = 0; t < 5; ++t) {
            short8 b = *(const short8*)(wfrag_l
                + ((size_t)(c * NTILES + nt0 + t) * 64 + lane) * 8);
            acc[t][0] = __builtin_amdgcn_mfma_f32_16x16x32_bf16(a0, b, acc[t][0], 0, 0, 0);
            acc[t][1] = __builtin_amdgcn_mfma_f32_16x16x32_bf16(a1, b, acc[t][1], 0, 0, 0);
        }
    }
    #pragma unroll
    for (int t = 0; t < 5; ++t) {
        int col = (nt0 + t) * 16 + m;
        if (col >= HID) continue;
        #pragma unroll
        for (int mt = 0; mt < 2; ++mt) {
            long rbase = (e0 + mt * 16 + quad * 4) * HP + col;
            #pragma unroll
            for (int r = 0; r < 4; ++r)
                C[rbase + (long)r * HP] = f2bf(acc[t][mt][r]);
        }
    }
}

// fused update+gemm (big path, layers 1,2): 32-edge block, LDS A-tile.
// phase 1: hn = relu(Sb[row] - hW[e^1] + h0buf[e])  -- pure loads, no W2 chain
// phase 2: R10's proven MFMA tiling (acc[5][2]).
__global__ __launch_bounds__(256) void fused_update_h0(
    ushort_t* h, const ushort_t* __restrict__ Sb,
    const ushort_t* __restrict__ h0buf, const int* __restrict__ row,
    const ushort_t* __restrict__ wfrag_l)
{
    __shared__ ushort_t At[32 * ATS];   // 20992 B
    __shared__ int rows[32];
    const int tid = threadIdx.x;
    const long e0 = (long)blockIdx.x * 32;
    if (tid < 32) rows[tid] = row[e0 + tid];
    __syncthreads();

    for (int i = tid; i < 16 * 80; i += 256) {  // 5 iters: pair p, quad g
        int p = i / 80, g = i % 80;
        int c0 = 4 * g;
        int la = 2 * p, lb = 2 * p + 1;
        ushort4 ova, ovb;
        if (g < 75) {
            long Ea = e0 + la, Eb = e0 + lb;
            int ra = rows[la], rb = rows[lb];
            ushort4 wa = *(const ushort4*)&h[Ea * HP + c0];
            ushort4 wb = *(const ushort4*)&h[Eb * HP + c0];
            ushort4 sa = *(const ushort4*)&Sb[(long)ra * HID + c0];
            ushort4 sb = *(const ushort4*)&Sb[(long)rb * HID + c0];
            ushort4 ha = *(const ushort4*)&h0buf[Ea * HP + c0];
            ushort4 hb = *(const ushort4*)&h0buf[Eb * HP + c0];
            ova.x = f2bf(fmaxf(bf2f(sa.x) - bf2f(wb.x) + bf2f(ha.x), 0.f));
            ova.y = f2bf(fmaxf(bf2f(sa.y) - bf2f(wb.y) + bf2f(ha.y), 0.f));
            ova.z = f2bf(fmaxf(bf2f(sa.z) - bf2f(wb.z) + bf2f(ha.z), 0.f));
            ova.w = f2bf(fmaxf(bf2f(sa.w) - bf2f(wb.w) + bf2f(ha.w), 0.f));
            ovb.x = f2bf(fmaxf(bf2f(sb.x) - bf2f(wa.x) + bf2f(hb.x), 0.f));
            ovb.y = f2bf(fmaxf(bf2f(sb.y) - bf2f(wa.y) + bf2f(hb.y), 0.f));
            ovb.z = f2bf(fmaxf(bf2f(sb.z) - bf2f(wa.z) + bf2f(hb.z), 0.f));
            ovb.w = f2bf(fmaxf(bf2f(sb.w) - bf2f(wa.w) + bf2f(hb.w), 0.f));
        } else {
            ova.x = 0; ova.y = 0; ova.z = 0; ova.w = 0;
            ovb = ova;
        }
        *(ushort4*)&At[la * ATS + c0] = ova;
        *(ushort4*)&At[lb * ATS + c0] = ovb;
    }
    __syncthreads();

    const int wave = tid >> 6, lane = tid & 63;
    const int quad = lane >> 4, m = lane & 15;
    const int nt0 = wave * 5;
    f32x4 acc[5][2];
    #pragma unroll
    for (int t = 0; t < 5; ++t)
        #pragma unroll
        for (int mt = 0; mt < 2; ++mt)
            acc[t][mt] = (f32x4){0.f, 0.f, 0.f, 0.f};

    for (int c = 0; c < 10; ++c) {
        short8 a[2];
        #pragma unroll
        for (int mt = 0; mt < 2; ++mt)
            a[mt] = *(const short8*)&At[(mt * 16 + m) * ATS + c * 32 + quad * 8];
        #pragma unroll
        for (int t = 0; t < 5; ++t) {
            short8 b = *(const short8*)(wfrag_l
                + ((size_t)(c * NTILES + nt0 + t) * 64 + lane) * 8);
            #pragma unroll
            for (int mt = 0; mt < 2; ++mt)
                acc[t][mt] = __builtin_amdgcn_mfma_f32_16x16x32_bf16(
                    a[mt], b, acc[t][mt], 0, 0, 0);
        }
    }
    #pragma unroll
    for (int t = 0; t < 5; ++t) {
        int col = (nt0 + t) * 16 + m;
        if (col >= HID) continue;
        #pragma unroll
        for (int mt = 0; mt < 2; ++mt) {
            long rbase = (e0 + mt * 16 + quad * 4) * HP + col;
            #pragma unroll
            for (int r = 0; r < 4; ++r)
                h[rbase + (long)r * HP] = f2bf(acc[t][mt][r]);
        }
    }
}

// final edge update (big path): h = relu(Sb[row] - hW[e^1] + h0buf[e])
__global__ __launch_bounds__(256) void edge_update_h0(
    ushort_t* h, const ushort_t* __restrict__ Sb,
    const ushort_t* __restrict__ h0buf, const int* __restrict__ row)
{
    __shared__ int rows[64];
    const int tid = threadIdx.x;
    const long e0 = (long)blockIdx.x * 64;
    if (tid < 64) rows[tid] = row[e0 + tid];
    __syncthreads();

    for (int i = tid; i < 32 * 75; i += 256) {
        int p = i / 75, g = i % 75;
        int c0 = 4 * g;
        int la = 2 * p, lb = 2 * p + 1;
        long Ea = e0 + la, Eb = e0 + lb;
        int ra = rows[la], rb = rows[lb];
        ushort4 wa = *(const ushort4*)&h[Ea * HP + c0];
        ushort4 wb = *(const ushort4*)&h[Eb * HP + c0];
        ushort4 sa = *(const ushort4*)&Sb[(long)ra * HID + c0];
        ushort4 sb = *(const ushort4*)&Sb[(long)rb * HID + c0];
        ushort4 ha = *(const ushort4*)&h0buf[Ea * HP + c0];
        ushort4 hb = *(const ushort4*)&h0buf[Eb * HP + c0];
        ushort4 ova, ovb;
        ova.x = f2bf(fmaxf(bf2f(sa.x) - bf2f(wb.x) + bf2f(ha.x), 0.f));
        ova.y = f2bf(fmaxf(bf2f(sa.y) - bf2f(wb.y) + bf2f(ha.y), 0.f));
        ova.z = f2bf(fmaxf(bf2f(sa.z) - bf2f(wb.z) + bf2f(ha.z), 0.f));
        ova.w = f2bf(fmaxf(bf2f(sa.w) - bf2f(wb.w) + bf2f(ha.w), 0.f));
        ovb.x = f2bf(fmaxf(bf2f(sb.x) - bf2f(wa.x) + bf2f(hb.x), 0.f));
        ovb.y = f2bf(fmaxf(bf2f(sb.y) - bf2f(wa.y) + bf2f(hb.y), 0.f));
        ovb.z = f2bf(fmaxf(bf2f(sb.z) - bf2f(wa.z) + bf2f(hb.z), 0.f));
        ovb.w = f2bf(fmaxf(bf2f(sb.w) - bf2f(wa.w) + bf2f(hb.w), 0.f));
        ((ushort4*)h)[Ea * (HP / 4) + g] = ova;
        ((ushort4*)h)[Eb * (HP / 4) + g] = ovb;
    }
}

// ---- small-ws fallback: R10's fused conv (W2 recompute) + update ----
template<bool UPDATE>
__global__ __launch_bounds__(256) void fused_conv(
    ushort_t* h, const ushort_t* __restrict__ Sb,
    const ushort_t* __restrict__ xW1b, const float* __restrict__ edge_attr,
    const float* __restrict__ W2, const int* __restrict__ row,
    const ushort_t* __restrict__ wfrag_l)
{
    __shared__ ushort_t At[32 * ATS];
    __shared__ float eas[32 * 16];
    __shared__ int rows[32];
    const int tid = threadIdx.x;
    const long e0 = (long)blockIdx.x * 32;

    for (int i = tid; i < 32 * 16; i += 256)
        eas[i] = edge_attr[e0 * 16 + i];
    if (tid < 32) rows[tid] = row[e0 + tid];
    __syncthreads();

    for (int i = tid; i < 16 * 80; i += 256) {
        int p = i / 80, g = i % 80;
        int c0 = 4 * g;
        int la = 2 * p, lb = 2 * p + 1;
        ushort4 ova, ovb;
        if (g < 75) {
            long Ea = e0 + la, Eb = e0 + lb;
            int ra = rows[la], rb = rows[lb];
            ushort4 xa = *(const ushort4*)&xW1b[(long)ra * HID + c0];
            ushort4 xb = *(const ushort4*)&xW1b[(long)rb * HID + c0];
            float h0a[4] = {bf2f(xa.x), bf2f(xa.y), bf2f(xa.z), bf2f(xa.w)};
            float h0b[4] = {bf2f(xb.x), bf2f(xb.y), bf2f(xb.z), bf2f(xb.w)};
            #pragma unroll
            for (int k = 0; k < 16; ++k) {
                float aa = eas[la * 16 + k];
                float ab = eas[lb * 16 + k];
                const float4 w = *(const float4*)&W2[(long)k * HID + c0];
                h0a[0] = fmaf(aa, w.x, h0a[0]); h0b[0] = fmaf(ab, w.x, h0b[0]);
                h0a[1] = fmaf(aa, w.y, h0a[1]); h0b[1] = fmaf(ab, w.y, h0b[1]);
                h0a[2] = fmaf(aa, w.z, h0a[2]); h0b[2] = fmaf(ab, w.z, h0b[2]);
                h0a[3] = fmaf(aa, w.w, h0a[3]); h0b[3] = fmaf(ab, w.w, h0b[3]);
            }
            if (UPDATE) {
                ushort4 wa = *(const ushort4*)&h[Ea * HP + c0];
                ushort4 wb = *(const ushort4*)&h[Eb * HP + c0];
                ushort4 sa = *(const ushort4*)&Sb[(long)ra * HID + c0];
                ushort4 sb = *(const ushort4*)&Sb[(long)rb * HID + c0];
                ova.x = f2bf(fmaxf(bf2f(sa.x) - bf2f(wb.x) + fmaxf(h0a[0], 0.f), 0.f));
                ova.y = f2bf(fmaxf(bf2f(sa.y) - bf2f(wb.y) + fmaxf(h0a[1], 0.f), 0.f));
                ova.z = f2bf(fmaxf(bf2f(sa.z) - bf2f(wb.z) + fmaxf(h0a[2], 0.f), 0.f));
                ova.w = f2bf(fmaxf(bf2f(sa.w) - bf2f(wb.w) + fmaxf(h0a[3], 0.f), 0.f));
                ovb.x = f2bf(fmaxf(bf2f(sb.x) - bf2f(wa.x) + fmaxf(h0b[0], 0.f), 0.f));
                ovb.y = f2bf(fmaxf(bf2f(sb.y) - bf2f(wa.y) + fmaxf(h0b[1], 0.f), 0.f));
                ovb.z = f2bf(fmaxf(bf2f(sb.z) - bf2f(wa.z) + fmaxf(h0b[2], 0.f), 0.f));
                ovb.w = f2bf(fmaxf(bf2f(sb.w) - bf2f(wa.w) + fmaxf(h0b[3], 0.f), 0.f));
            } else {
                ova.x = f2bf(fmaxf(h0a[0], 0.f)); ova.y = f2bf(fmaxf(h0a[1], 0.f));
                ova.z = f2bf(fmaxf(h0a[2], 0.f)); ova.w = f2bf(fmaxf(h0a[3], 0.f));
                ovb.x = f2bf(fmaxf(h0b[0], 0.f)); ovb.y = f2bf(fmaxf(h0b[1], 0.f));
                ovb.z = f2bf(fmaxf(h0b[2], 0.f)); ovb.w = f2bf(fmaxf(h0b[3], 0.f));
            }
        } else {
            ova.x = 0; ova.y = 0; ova.z = 0; ova.w = 0;
            ovb = ova;
        }
        *(ushort4*)&At[la * ATS + c0] = ova;
        *(ushort4*)&At[lb * ATS + c0] = ovb;
    }
    __syncthreads();

    const int wave = tid >> 6, lane = tid & 63;
    const int quad = lane >> 4, m = lane & 15;
    const int nt0 = wave * 5;
    f32x4 acc[5][2];
    #pragma unroll
    for (int t = 0; t < 5; ++t)
        #pragma unroll
        for (int mt = 0; mt < 2; ++mt)
            acc[t][mt] = (f32x4){0.f, 0.f, 0.f, 0.f};

    for (int c = 0; c < 10; ++c) {
        short8 a[2];
        #pragma unroll
        for (int mt = 0; mt < 2; ++mt)
            a[mt] = *(const short8*)&At[(mt * 16 + m) * ATS + c * 32 + quad * 8];
        #pragma unroll
        for (int t = 0; t < 5; ++t) {
            short8 b = *(const short8*)(wfrag_l
                + ((size_t)(c * NTILES + nt0 + t) * 64 + lane) * 8);
            #pragma unroll
            for (int mt = 0; mt < 2; ++mt)
                acc[t][mt] = __builtin_amdgcn_mfma_f32_16x16x32_bf16(
                    a[mt], b, acc[t][mt], 0, 0, 0);
        }
    }
    #pragma unroll
    for (int t = 0; t < 5; ++t) {
        int col = (nt0 + t) * 16 + m;
        if (col >= HID) continue;
        #pragma unroll
        for (int mt = 0; mt < 2; ++mt) {
            long rbase = (e0 + mt * 16 + quad * 4) * HP + col;
            #pragma unroll
            for (int r = 0; r < 4; ++r)
                h[rbase + (long)r * HP] = f2bf(acc[t][mt][r]);
        }
    }
}

__global__ __launch_bounds__(256) void edge_update_pairs(
    ushort_t* h, const ushort_t* __restrict__ Sb,
    const ushort_t* __restrict__ xW1b, const float* __restrict__ edge_attr,
    const float* __restrict__ W2, const int* __restrict__ row)
{
    __shared__ float eas[64 * 16];
    __shared__ int rows[64];
    const int tid = threadIdx.x;
    const long e0 = (long)blockIdx.x * 64;

    for (int i = tid; i < 64 * 16; i += 256)
        eas[i] = edge_attr[e0 * 16 + i];
    if (tid < 64) rows[tid] = row[e0 + tid];
    __syncthreads();

    for (int i = tid; i < 32 * 75; i += 256) {
        int p = i / 75, g = i % 75;
        int c0 = 4 * g;
        int la = 2 * p, lb = 2 * p + 1;
        long Ea = e0 + la, Eb = e0 + lb;
        int ra = rows[la], rb = rows[lb];
        ushort4 wa = *(const ushort4*)&h[Ea * HP + c0];
        ushort4 wb = *(const ushort4*)&h[Eb * HP + c0];
        ushort4 sa = *(const ushort4*)&Sb[(long)ra * HID + c0];
        ushort4 sb = *(const ushort4*)&Sb[(long)rb * HID + c0];
        ushort4 xa = *(const ushort4*)&xW1b[(long)ra * HID + c0];
        ushort4 xb = *(const ushort4*)&xW1b[(long)rb * HID + c0];
        float h0a[4] = {bf2f(xa.x), bf2f(xa.y), bf2f(xa.z), bf2f(xa.w)};
        float h0b[4] = {bf2f(xb.x), bf2f(xb.y), bf2f(xb.z), bf2f(xb.w)};
        #pragma unroll
        for (int k = 0; k < 16; ++k) {
            float aa = eas[la * 16 + k];
            float ab = eas[lb * 16 + k];
            const float4 w0 = *(const float4*)&W2[(long)k * HID + c0];
            h0a[0] = fmaf(aa, w0.x, h0a[0]); h0b[0] = fmaf(ab, w0.x, h0b[0]);
            h0a[1] = fmaf(aa, w0.y, h0a[1]); h0b[1] = fmaf(ab, w0.y, h0b[1]);
            h0a[2] = fmaf(aa, w0.z, h0a[2]); h0b[2] = fmaf(ab, w0.z, h0b[2]);
            h0a[3] = fmaf(aa, w0.w, h0a[3]); h0b[3] = fmaf(ab, w0.w, h0b[3]);
        }
        ushort4 ova, ovb;
        ova.x = f2bf(fmaxf(bf2f(sa.x) - bf2f(wb.x) + fmaxf(h0a[0], 0.f), 0.f));
        ova.y = f2bf(fmaxf(bf2f(sa.y) - bf2f(wb.y) + fmaxf(h0a[1], 0.f), 0.f));
        ova.z = f2bf(fmaxf(bf2f(sa.z) - bf2f(wb.z) + fmaxf(h0a[2], 0.f), 0.f));
        ova.w = f2bf(fmaxf(bf2f(sa.w) - bf2f(wb.w) + fmaxf(h0a[3], 0.f), 0.f));
        ovb.x = f2bf(fmaxf(bf2f(sb.x) - bf2f(wa.x) + fmaxf(h0b[0], 0.f), 0.f));
        ovb.y = f2bf(fmaxf(bf2f(sb.y) - bf2f(wa.y) + fmaxf(h0b[1], 0.f), 0.f));
        ovb.z = f2bf(fmaxf(bf2f(sb.z) - bf2f(wa.z) + fmaxf(h0b[2], 0.f), 0.f));
        ovb.w = f2bf(fmaxf(bf2f(sb.w) - bf2f(wa.w) + fmaxf(h0b[3], 0.f), 0.f));
        ((ushort4*)h)[Ea * (HP / 4) + g] = ova;
        ((ushort4*)h)[Eb * (HP / 4) + g] = ovb;
    }
}

// K4: Sb[n][:] = bf16( bias[:] + segsum );  stride HID
__global__ __launch_bounds__(256) void gather_sum(
    const ushort_t* __restrict__ src, const int* __restrict__ offsets,
    const int* __restrict__ ends, const int* __restrict__ eid,
    const float* __restrict__ bias, ushort_t* __restrict__ Sb)
{
    long idx = (long)blockIdx.x * 256 + threadIdx.x;
    if (idx >= (long)N_NODES * 75) return;
    int n = (int)(idx / 75);
    int g = (int)(idx % 75);
    int beg = offsets[n], end = ends[n];
    float a0 = 0.f, a1 = 0.f, a2 = 0.f, a3 = 0.f;
    float b0 = 0.f, b1 = 0.f, b2 = 0.f, b3 = 0.f;
    int j = beg;
    for (; j + 1 < end; j += 2) {
        int e0i = eid[j], e1i = eid[j + 1];
        ushort4 v0 = ((const ushort4*)src)[(long)e0i * (HP / 4) + g];
        ushort4 v1 = ((const ushort4*)src)[(long)e1i * (HP / 4) + g];
        a0 += bf2f(v0.x); a1 += bf2f(v0.y); a2 += bf2f(v0.z); a3 += bf2f(v0.w);
        b0 += bf2f(v1.x); b1 += bf2f(v1.y); b2 += bf2f(v1.z); b3 += bf2f(v1.w);
    }
    if (j < end) {
        int e0i = eid[j];
        ushort4 v0 = ((const ushort4*)src)[(long)e0i * (HP / 4) + g];
        a0 += bf2f(v0.x); a1 += bf2f(v0.y); a2 += bf2f(v0.z); a3 += bf2f(v0.w);
    }
    float4 bv = *(const float4*)&bias[4 * g];
    ushort4 o;
    o.x = f2bf(a0 + b0 + bv.x); o.y = f2bf(a1 + b1 + bv.y);
    o.z = f2bf(a2 + b2 + bv.z); o.w = f2bf(a3 + b3 + bv.w);
    *(ushort4*)&Sb[(long)n * HID + 4 * g] = o;
}

// K4b: final gather -> bf16 into Ab cols 64..363
__global__ __launch_bounds__(256) void gather_ab(
    const ushort_t* __restrict__ src, const int* __restrict__ offsets,
    const int* __restrict__ ends, const int* __restrict__ eid,
    ushort_t* __restrict__ Ab)
{
    long idx = (long)blockIdx.x * 256 + threadIdx.x;
    if (idx >= (long)N_NODES * 75) return;
    int n = (int)(idx / 75);
    int g = (int)(idx % 75);
    int beg = offsets[n], end = ends[n];
    float a0 = 0.f, a1 = 0.f, a2 = 0.f, a3 = 0.f;
    float b0 = 0.f, b1 = 0.f, b2 = 0.f, b3 = 0.f;
    int j = beg;
    for (; j + 1 < end; j += 2) {
        int e0i = eid[j], e1i = eid[j + 1];
        ushort4 v0 = ((const ushort4*)src)[(long)e0i * (HP / 4) + g];
        ushort4 v1 = ((const ushort4*)src)[(long)e1i * (HP / 4) + g];
        a0 += bf2f(v0.x); a1 += bf2f(v0.y); a2 += bf2f(v0.z); a3 += bf2f(v0.w);
        b0 += bf2f(v1.x); b1 += bf2f(v1.y); b2 += bf2f(v1.z); b3 += bf2f(v1.w);
    }
    if (j < end) {
        int e0i = eid[j];
        ushort4 v0 = ((const ushort4*)src)[(long)e0i * (HP / 4) + g];
        a0 += bf2f(v0.x); a1 += bf2f(v0.y); a2 += bf2f(v0.z); a3 += bf2f(v0.w);
    }
    ushort4 o;
    o.x = f2bf(a0 + b0); o.y = f2bf(a1 + b1);
    o.z = f2bf(a2 + b2); o.w = f2bf(a3 + b3);
    *(ushort4*)&Ab[(long)n * KE2N + 64 + 4 * g] = o;
}

__global__ __launch_bounds__(256) void x_fill(
    const float* __restrict__ x, ushort_t* __restrict__ Ab)
{
    long idx = (long)blockIdx.x * 256 + threadIdx.x;
    if (idx >= (long)N_NODES * 21) return;
    int n = (int)(idx / 21);
    int q = (int)(idx % 21);
    ushort4 o;
    if (q < 16) {
        float4 v = *(const float4*)&x[(long)n * 64 + 4 * q];
        o.x = f2bf(v.x); o.y = f2bf(v.y); o.z = f2bf(v.z); o.w = f2bf(v.w);
        *(ushort4*)&Ab[(long)n * KE2N + 4 * q] = o;
    } else {
        o.x = 0; o.y = 0; o.z = 0; o.w = 0;
        *(ushort4*)&Ab[(long)n * KE2N + 364 + 4 * (q - 16)] = o;
    }
}

// K7: hn = relu(Ab @ W_e2n + b)
__global__ __launch_bounds__(256) void e2n_mfma(
    const ushort_t* __restrict__ Ab, const ushort_t* __restrict__ wfrag2,
    const float* __restrict__ b_e2n, float* __restrict__ hn)
{
    const int tid = threadIdx.x;
    const int wave = tid >> 6, lane = tid & 63;
    const int quad = lane >> 4, m = lane & 15;
    const long n0 = (long)blockIdx.x * 64;
    const int nt0 = wave * 5;

    f32x4 acc[5][4];
    #pragma unroll
    for (int t = 0; t < 5; ++t)
        #pragma unroll
        for (int mt = 0; mt < 4; ++mt)
            acc[t][mt] = (f32x4){0.f, 0.f, 0.f, 0.f};

    for (int c = 0; c < 12; ++c) {
        short8 a[4];
        #pragma unroll
        for (int mt = 0; mt < 4; ++mt) {
            long r = n0 + mt * 16 + m;
            if (r > N_NODES - 1) r = N_NODES - 1;
            a[mt] = *(const short8*)(Ab + r * KE2N + c * 32 + quad * 8);
        }
        #pragma unroll
        for (int t = 0; t < 5; ++t) {
            short8 b = *(const short8*)(wfrag2
                + ((size_t)(c * NTILES + nt0 + t) * 64 + lane) * 8);
            #pragma unroll
            for (int mt = 0; mt < 4; ++mt)
                acc[t][mt] = __builtin_amdgcn_mfma_f32_16x16x32_bf16(
                    a[mt], b, acc[t][mt], 0, 0, 0);
        }
    }

    #pragma unroll
    for (int t = 0; t < 5; ++t) {
        int col = (nt0 + t) * 16 + m;
        if (col >= HID) continue;
        float bias = b_e2n[col];
        #pragma unroll
        for (int mt = 0; mt < 4; ++mt) {
            long rw = n0 + mt * 16 + quad * 4;
            #pragma unroll
            for (int r = 0; r < 4; ++r) {
                long rowi = rw + r;
                if (rowi < N_NODES)
                    hn[rowi * HP + col] = fmaxf(acc[t][mt][r] + bias, 0.f);
            }
        }
    }
}

__global__ __launch_bounds__(256) void pool_graph(
    const float* __restrict__ hn, const int* __restrict__ goff,
    float* __restrict__ pooled)
{
    int g = blockIdx.x;
    int beg = goff[g], end = goff[g + 1];
    for (int c = threadIdx.x; c < HID; c += 256) {
        float acc = 0.f;
        for (int n = beg; n < end; ++n)
            acc += hn[(long)n * HP + c];
        pooled[(long)g * HID + c] = acc;
    }
}

__global__ __launch_bounds__(64) void ffn_out(
    const float* __restrict__ pooled, const float* __restrict__ W_ffn,
    const float* __restrict__ b_ffn, float* __restrict__ out)
{
    int g = blockIdx.x;
    int lane = threadIdx.x;
    float s = 0.f;
    for (int c = lane; c < HID; c += 64)
        s += pooled[(long)g * HID + c] * W_ffn[c];
    #pragma unroll
    for (int off = 32; off > 0; off >>= 1)
        s += __shfl_down(s, off, 64);
    if (lane == 0) out[g] = s + b_ffn[0];
}

extern "C" void kernel_launch(void* const* d_in, const int* in_sizes, int n_in,
                              void* d_out, int out_size, void* d_ws, size_t ws_size,
                              hipStream_t stream) {
    const float* x         = (const float*)d_in[0];
    const float* edge_attr = (const float*)d_in[1];
    const int*   edge_index= (const int*)d_in[2];
    const int*   batch     = (const int*)d_in[3];
    const float* W_init    = (const float*)d_in[4];
    const float* b_init    = (const float*)d_in[5];
    const float* W_convs   = (const float*)d_in[6];
    const float* b_convs   = (const float*)d_in[7];
    const float* W_e2n     = (const float*)d_in[8];
    const float* b_e2n     = (const float*)d_in[9];
    const float* W_ffn     = (const float*)d_in[10];
    const float* b_ffn     = (const float*)d_in[11];
    float* out = (float*)d_out;

    const int* row = edge_index;
    const int* col = edge_index + N_EDGES;
    const float* W2 = W_init + (size_t)F_NODE * HID;

    const size_t SZ_H   = (size_t)N_EDGES * HP * 2;     // 204.8 MB
    const size_t SZ_SB  = (size_t)N_NODES * HID * 2;    // 12 MB
    const size_t SZ_AB  = (size_t)N_NODES * KE2N * 2;   // 15.36 MB (xW1b aliased here)
    const size_t SZ_MISC = (size_t)N_GRAPHS * HID * 4
                         + (size_t)N_NODES * 4 * 2 + (size_t)N_EDGES * 4
                         + (size_t)DEPTH * WFRAG_USHORT_PER_LAYER * 2
                         + (size_t)W2FRAG_USHORT * 2
                         + (size_t)(N_GRAPHS + 1 + N_GRAPHS) * 4 + 32768;
    const size_t need_small = SZ_H + SZ_SB + SZ_AB + SZ_MISC;
    const size_t need_big   = need_small + SZ_H;        // + h0buf
    if (ws_size < need_small) return;  // clean absmax fail
    const bool big = (ws_size >= need_big);

    char* p = (char*)d_ws;
    auto take = [&](size_t bytes) {
        char* q = p;
        p += (bytes + 255) & ~(size_t)255;
        return q;
    };
    ushort_t* h       = (ushort_t*)take(SZ_H);
    ushort_t* h0buf   = big ? (ushort_t*)take(SZ_H) : nullptr;
    ushort_t* Sb      = (ushort_t*)take(SZ_SB);
    ushort_t* Ab      = (ushort_t*)take(SZ_AB);
    float*    pooled  = (float*)take((size_t)N_GRAPHS * HID * 4);
    int*      cursor  = (int*)take((size_t)N_NODES * 4);
    int*      offsets = (int*)take((size_t)N_NODES * 4);
    int*      eid     = (int*)take((size_t)N_EDGES * 4);
    ushort_t* wfrag   = (ushort_t*)take((size_t)DEPTH * WFRAG_USHORT_PER_LAYER * 2);
    ushort_t* wfrag2  = (ushort_t*)take((size_t)W2FRAG_USHORT * 2);
    int*      gdeg    = (int*)take((size_t)N_GRAPHS * 4);
    int*      goff    = (int*)take((size_t)(N_GRAPHS + 1) * 4);

    ushort_t* xW1b = Ab;        // alias: xW1b dead before x_fill writes Ab
    float*    hn   = (float*)h; // alias: h dead after gather_ab

    // CSR + graph-offset build
    hipMemsetAsync(cursor, 0, (size_t)N_NODES * 4, stream);
    hipMemsetAsync(gdeg, 0, (size_t)N_GRAPHS * 4, stream);
    csr_hist<<<N_EDGES / 256, 256, 0, stream>>>(col, cursor);
    csr_scan<<<1, 256, 0, stream>>>(cursor, offsets, cursor);
    csr_fill<<<N_EDGES / 256, 256, 0, stream>>>(col, cursor, eid);
    ghist<<<(N_NODES + 255) / 256, 256, 0, stream>>>(batch, gdeg);
    gscan<<<1, 128, 0, stream>>>(gdeg, goff);

    wfrag_build<<<dim3(10, NTILES, DEPTH), 64, 0, stream>>>(W_convs, wfrag);
    wfrag2_build<<<dim3(12, NTILES, 1), 64, 0, stream>>>(W_e2n, wfrag2);

    node_init_gemm<<<N_NODES / 16, 256, 0, stream>>>(x, W_init, b_init, xW1b);

    const int GS_GRID = ((N_NODES * 75) + 255) / 256;

    if (big) {
        // h0 computed ONCE; conv layers are load-only updates + MFMA
        h0_build<<<N_EDGES / 16, 256, 0, stream>>>(
            edge_attr, row, xW1b, W_init, h0buf);
        gemm0_mfma<<<N_EDGES / 32, 256, 0, stream>>>(h0buf, wfrag, h);
        gather_sum<<<GS_GRID, 256, 0, stream>>>(
            h, offsets, cursor, eid, b_convs + 0 * HID, Sb);
        fused_update_h0<<<N_EDGES / 32, 256, 0, stream>>>(
            h, Sb, h0buf, row, wfrag + 1 * (size_t)WFRAG_USHORT_PER_LAYER);
        gather_sum<<<GS_GRID, 256, 0, stream>>>(
            h, offsets, cursor, eid, b_convs + 1 * HID, Sb);
        fused_update_h0<<<N_EDGES / 32, 256, 0, stream>>>(
            h, Sb, h0buf, row, wfrag + 2 * (size_t)WFRAG_USHORT_PER_LAYER);
        gather_sum<<<GS_GRID, 256, 0, stream>>>(
            h, offsets, cursor, eid, b_convs + 2 * HID, Sb);
        edge_update_h0<<<N_EDGES / 64, 256, 0, stream>>>(h, Sb, h0buf, row);
    } else {
        // R10 fallback (recompute h0 per layer)
        fused_conv<false><<<N_EDGES / 32, 256, 0, stream>>>(
            h, Sb, xW1b, edge_attr, W2, row, wfrag);
        gather_sum<<<GS_GRID, 256, 0, stream>>>(
            h, offsets, cursor, eid, b_convs + 0 * HID, Sb);
        fused_conv<true><<<N_EDGES / 32, 256, 0, stream>>>(
            h, Sb, xW1b, edge_attr, W2, row, wfrag + 1 * (size_t)WFRAG_USHORT_PER_LAYER);
        gather_sum<<<GS_GRID, 256, 0, stream>>>(
            h, offsets, cursor, eid, b_convs + 1 * HID, Sb);
        fused_conv<true><<<N_EDGES / 32, 256, 0, stream>>>(
            h, Sb, xW1b, edge_attr, W2, row, wfrag + 2 * (size_t)WFRAG_USHORT_PER_LAYER);
        gather_sum<<<GS_GRID, 256, 0, stream>>>(
            h, offsets, cursor, eid, b_convs + 2 * HID, Sb);
        edge_update_pairs<<<N_EDGES / 64, 256, 0, stream>>>(
            h, Sb, xW1b, edge_attr, W2, row);
    }

    // ---- e2n path ----
    x_fill<<<((N_NODES * 21) + 255) / 256, 256, 0, stream>>>(x, Ab);
    gather_ab<<<GS_GRID, 256, 0, stream>>>(h, offsets, cursor, eid, Ab);
    e2n_mfma<<<(N_NODES + 63) / 64, 256, 0, stream>>>(Ab, wfrag2, b_e2n, hn);
    pool_graph<<<N_GRAPHS, 256, 0, stream>>>(hn, goff, pooled);
    ffn_out<<<N_GRAPHS, 64, 0, stream>>>(pooled, W_ffn, b_ffn, out);
}

// Round 13
// 1258.593 us; speedup vs baseline: 1.8337x; 1.2434x over previous
//
#include <hip/hip_runtime.h>
#include <hip/hip_bf16.h>

typedef unsigned short ushort_t;
typedef __attribute__((ext_vector_type(8))) short short8;   // 8 bf16 = 4 VGPRs
typedef __attribute__((ext_vector_type(4))) float f32x4;    // MFMA C/D

#define N_NODES 20000
#define N_EDGES 320000
#define F_NODE 64
#define F_EDGE 16
#define HID 300
#define HP 320          // padded hidden: row stride of h
#define NTILES 20       // wfrag n-tiles; tile 19 pure pad
#define DEPTH 3
#define N_GRAPHS 128
#define KE2N 384        // e2n K: 64 (x) + 300 (S) + 20 pad
#define ATS 328         // LDS A-tile row stride (ushorts)

#define WFRAG_USHORT_PER_LAYER (10 * NTILES * 64 * 8)  // 102400 ushorts
#define W2FRAG_USHORT (NTILES * 64 * 8)                // 10240 ushorts (1 K-chunk)
#define WE2NFRAG_USHORT (12 * NTILES * 64 * 8)         // 122880 ushorts

__device__ __forceinline__ float bf2f(ushort_t u) {
    union { unsigned int i; float f; } v;
    v.i = ((unsigned int)u) << 16;
    return v.f;
}
__device__ __forceinline__ ushort_t f2bf(float f) {
    union { float f; unsigned int i; } v;
    v.f = f;
    unsigned int x = v.i;
    unsigned int r = x + 0x7fffu + ((x >> 16) & 1u);  // RNE
    return (ushort_t)(r >> 16);
}
__device__ __forceinline__ unsigned int fpack(float lo, float hi) {
    return ((unsigned int)f2bf(lo)) | (((unsigned int)f2bf(hi)) << 16);
}

// ---------------- CSR build ----------------
__global__ __launch_bounds__(256) void csr_hist(
    const int* __restrict__ col, int* __restrict__ deg)
{
    int e = blockIdx.x * 256 + threadIdx.x;
    atomicAdd(&deg[col[e]], 1);
}

__global__ __launch_bounds__(256) void csr_scan(
    const int* __restrict__ deg, int* __restrict__ offsets,
    int* __restrict__ cursor)
{
    __shared__ int sums[256];
    const int t = threadIdx.x;
    const int CH = 79;
    int base = t * CH;
    int local = 0;
    for (int i = 0; i < CH; ++i) {
        int idx = base + i;
        if (idx < N_NODES) local += deg[idx];
    }
    sums[t] = local;
    __syncthreads();
    for (int off = 1; off < 256; off <<= 1) {
        int v = (t >= off) ? sums[t - off] : 0;
        __syncthreads();
        sums[t] += v;
        __syncthreads();
    }
    int run = (t > 0) ? sums[t - 1] : 0;
    for (int i = 0; i < CH; ++i) {
        int idx = base + i;
        if (idx < N_NODES) {
            offsets[idx] = run;
            cursor[idx] = run;
            run += deg[idx];
        }
    }
}

__global__ __launch_bounds__(256) void csr_fill(
    const int* __restrict__ col, int* __restrict__ cursor,
    int* __restrict__ eid)
{
    int e = blockIdx.x * 256 + threadIdx.x;
    int pos = atomicAdd(&cursor[col[e]], 1);
    eid[pos] = e;
}

__global__ __launch_bounds__(256) void ghist(
    const int* __restrict__ batch, int* __restrict__ gdeg)
{
    int n = blockIdx.x * 256 + threadIdx.x;
    if (n < N_NODES) atomicAdd(&gdeg[batch[n]], 1);
}

__global__ __launch_bounds__(128) void gscan(
    const int* __restrict__ gdeg, int* __restrict__ goff)
{
    __shared__ int s[128];
    int t = threadIdx.x;
    int d = gdeg[t];
    s[t] = d;
    __syncthreads();
    for (int off = 1; off < 128; off <<= 1) {
        int v = (t >= off) ? s[t - off] : 0;
        __syncthreads();
        s[t] += v;
        __syncthreads();
    }
    goff[t] = s[t] - d;
    if (t == 127) goff[128] = s[127];
}

// ---------------- W fragment pre-packs ----------------
__global__ __launch_bounds__(64) void wfrag_build(
    const float* __restrict__ W_convs, ushort_t* __restrict__ wfrag)
{
    const int c = blockIdx.x, t = blockIdx.y, l = blockIdx.z;
    const int lane = threadIdx.x;
    const int k0 = c * 32 + (lane >> 4) * 8;
    const int n  = t * 16 + (lane & 15);
    ushort_t* dst = wfrag + (size_t)l * WFRAG_USHORT_PER_LAYER
                  + ((size_t)(c * NTILES + t) * 64 + lane) * 8;
    const float* Wl = W_convs + (size_t)l * HID * HID;
    #pragma unroll
    for (int j = 0; j < 8; ++j) {
        int k = k0 + j;
        float v = (k < HID && n < HID) ? Wl[(long)k * HID + n] : 0.f;
        dst[j] = f2bf(v);
    }
}

__global__ __launch_bounds__(64) void wfrag2_build(
    const float* __restrict__ W_e2n, ushort_t* __restrict__ wfrag2)
{
    const int c = blockIdx.x, t = blockIdx.y;
    const int lane = threadIdx.x;
    const int k0 = c * 32 + (lane >> 4) * 8;
    const int n  = t * 16 + (lane & 15);
    ushort_t* dst = wfrag2 + ((size_t)(c * NTILES + t) * 64 + lane) * 8;
    #pragma unroll
    for (int j = 0; j < 8; ++j) {
        int k = k0 + j;
        float v = (k < F_NODE + HID && n < HID) ? W_e2n[(long)k * HID + n] : 0.f;
        dst[j] = f2bf(v);
    }
}

// W2 (= W_init rows 64..79) as ONE 16x16x32 B-chunk: B[k][n], k<16 real, else 0
__global__ __launch_bounds__(64) void w2frag_build(
    const float* __restrict__ W2, ushort_t* __restrict__ w2frag)
{
    const int t = blockIdx.x;           // n-tile 0..19
    const int lane = threadIdx.x;
    const int k0 = (lane >> 4) * 8;
    const int n  = t * 16 + (lane & 15);
    ushort_t* dst = w2frag + ((size_t)t * 64 + lane) * 8;
    #pragma unroll
    for (int j = 0; j < 8; ++j) {
        int k = k0 + j;
        float v = (k < F_EDGE && n < HID) ? W2[(long)k * HID + n] : 0.f;
        dst[j] = f2bf(v);
    }
}

// ---------------- kernels ----------------

// K1: xW1b[n][c] = bf16(b_init[c] + x[n] @ W_init[0:64]);  stride HID
__global__ __launch_bounds__(256) void node_init_gemm(
    const float* __restrict__ x, const float* __restrict__ W_init,
    const float* __restrict__ b_init, ushort_t* __restrict__ xW1b)
{
    __shared__ float xs[16 * 64];
    const int tid = threadIdx.x;
    const long n0 = (long)blockIdx.x * 16;
    for (int i = tid; i < 16 * 64; i += 256) xs[i] = x[n0 * 64 + i];
    __syncthreads();
    const int nl = tid >> 4, ct = tid & 15;
    for (int q = 0; q < 19; ++q) {
        int c = ct + 16 * q;
        if (c < HID) {
            float acc = b_init[c];
            #pragma unroll 8
            for (int k = 0; k < 64; ++k)
                acc = fmaf(xs[nl * 64 + k], W_init[(long)k * HID + c], acc);
            xW1b[(n0 + nl) * HID + c] = f2bf(acc);
        }
    }
}

// Fused conv layer, 32-edge blocks, 256 thr / 4 waves.
// phase 0: P = ea_tile @ W2 via MFMA (1 K-chunk, 10 MFMAs/wave) -> LDS At.
//          Moves the old 640-fma/thread VALU chain onto the matrix pipe.
// phase 1: per pair-quad thread (read-then-overwrite its OWN At slot):
//   UPDATE:  hnew = relu(Sb[row] - hW[e^1] + relu(xW1b[row] + P))
//   !UPDATE: hnew = relu(xW1b[row] + P)           (layer 0; h not read)
// phase 2: main MFMA h = A @ Wl (R10's proven acc[5][2] tiling).
// In-place safe: phase-1 h reads complete before barrier; stores touch only
// own tile rows, cols < 300 (pad cols of global h are never read).
template<bool UPDATE>
__global__ __launch_bounds__(256) void fused_conv(
    ushort_t* h, const ushort_t* __restrict__ Sb,
    const ushort_t* __restrict__ xW1b, const float* __restrict__ edge_attr,
    const int* __restrict__ row, const ushort_t* __restrict__ w2frag,
    const ushort_t* __restrict__ wfrag_l)
{
    __shared__ ushort_t At[32 * ATS];   // 20992 B (P, then A-tile)
    __shared__ int rows[32];
    const int tid = threadIdx.x;
    const int wave = tid >> 6, lane = tid & 63;
    const int quad = lane >> 4, m = lane & 15;
    const long e0 = (long)blockIdx.x * 32;
    if (tid < 32) rows[tid] = row[e0 + tid];

    // ---- phase 0: P = EA @ W2 (one 16x16x32 chunk; k>=16 zero) ----
    {
        short8 a_ea[2];
        #pragma unroll
        for (int mt = 0; mt < 2; ++mt) {
            union { uint4 u4; short8 s8; } af;
            if (quad < 2) {
                const float* eap = edge_attr + (e0 + mt * 16 + m) * 16 + quad * 8;
                float4 v0 = *(const float4*)eap;
                float4 v1 = *(const float4*)(eap + 4);
                af.u4.x = fpack(v0.x, v0.y); af.u4.y = fpack(v0.z, v0.w);
                af.u4.z = fpack(v1.x, v1.y); af.u4.w = fpack(v1.z, v1.w);
            } else {
                af.u4.x = 0; af.u4.y = 0; af.u4.z = 0; af.u4.w = 0;
            }
            a_ea[mt] = af.s8;
        }
        const int nt0 = wave * 5;
        #pragma unroll
        for (int t = 0; t < 5; ++t) {
            short8 b = *(const short8*)(w2frag + ((size_t)(nt0 + t) * 64 + lane) * 8);
            #pragma unroll
            for (int mt = 0; mt < 2; ++mt) {
                f32x4 pc = (f32x4){0.f, 0.f, 0.f, 0.f};
                pc = __builtin_amdgcn_mfma_f32_16x16x32_bf16(a_ea[mt], b, pc, 0, 0, 0);
                int c = (nt0 + t) * 16 + m;
                #pragma unroll
                for (int r = 0; r < 4; ++r)
                    At[(mt * 16 + quad * 4 + r) * ATS + c] = f2bf(pc[r]);
            }
        }
    }
    __syncthreads();   // P complete (+ rows)

    // ---- phase 1: edge update into At (each thread owns its slots) ----
    for (int i = tid; i < 16 * 80; i += 256) {
        int p = i / 80, g = i % 80;
        int c0 = 4 * g;
        int la = 2 * p, lb = 2 * p + 1;
        ushort4 ova, ovb;
        if (g < 75) {
            long Ea = e0 + la, Eb = e0 + lb;
            int ra = rows[la], rb = rows[lb];
            ushort4 xa = *(const ushort4*)&xW1b[(long)ra * HID + c0];
            ushort4 xb = *(const ushort4*)&xW1b[(long)rb * HID + c0];
            ushort4 pa = *(const ushort4*)&At[la * ATS + c0];
            ushort4 pb = *(const ushort4*)&At[lb * ATS + c0];
            float h0a[4], h0b[4];
            h0a[0] = fmaxf(bf2f(xa.x) + bf2f(pa.x), 0.f);
            h0a[1] = fmaxf(bf2f(xa.y) + bf2f(pa.y), 0.f);
            h0a[2] = fmaxf(bf2f(xa.z) + bf2f(pa.z), 0.f);
            h0a[3] = fmaxf(bf2f(xa.w) + bf2f(pa.w), 0.f);
            h0b[0] = fmaxf(bf2f(xb.x) + bf2f(pb.x), 0.f);
            h0b[1] = fmaxf(bf2f(xb.y) + bf2f(pb.y), 0.f);
            h0b[2] = fmaxf(bf2f(xb.z) + bf2f(pb.z), 0.f);
            h0b[3] = fmaxf(bf2f(xb.w) + bf2f(pb.w), 0.f);
            if (UPDATE) {
                ushort4 wa = *(const ushort4*)&h[Ea * HP + c0];
                ushort4 wb = *(const ushort4*)&h[Eb * HP + c0];
                ushort4 sa = *(const ushort4*)&Sb[(long)ra * HID + c0];
                ushort4 sb = *(const ushort4*)&Sb[(long)rb * HID + c0];
                ova.x = f2bf(fmaxf(bf2f(sa.x) - bf2f(wb.x) + h0a[0], 0.f));
                ova.y = f2bf(fmaxf(bf2f(sa.y) - bf2f(wb.y) + h0a[1], 0.f));
                ova.z = f2bf(fmaxf(bf2f(sa.z) - bf2f(wb.z) + h0a[2], 0.f));
                ova.w = f2bf(fmaxf(bf2f(sa.w) - bf2f(wb.w) + h0a[3], 0.f));
                ovb.x = f2bf(fmaxf(bf2f(sb.x) - bf2f(wa.x) + h0b[0], 0.f));
                ovb.y = f2bf(fmaxf(bf2f(sb.y) - bf2f(wa.y) + h0b[1], 0.f));
                ovb.z = f2bf(fmaxf(bf2f(sb.z) - bf2f(wa.z) + h0b[2], 0.f));
                ovb.w = f2bf(fmaxf(bf2f(sb.w) - bf2f(wa.w) + h0b[3], 0.f));
            } else {
                ova.x = f2bf(h0a[0]); ova.y = f2bf(h0a[1]);
                ova.z = f2bf(h0a[2]); ova.w = f2bf(h0a[3]);
                ovb.x = f2bf(h0b[0]); ovb.y = f2bf(h0b[1]);
                ovb.z = f2bf(h0b[2]); ovb.w = f2bf(h0b[3]);
            }
        } else {
            ova.x = 0; ova.y = 0; ova.z = 0; ova.w = 0;  // K-pad cols 300..319
            ovb = ova;
        }
        *(ushort4*)&At[la * ATS + c0] = ova;
        *(ushort4*)&At[lb * ATS + c0] = ovb;
    }
    __syncthreads();   // A tile complete; all h reads done

    // ---- phase 2: main MFMA ----
    const int nt0 = wave * 5;
    f32x4 acc[5][2];
    #pragma unroll
    for (int t = 0; t < 5; ++t)
        #pragma unroll
        for (int mt = 0; mt < 2; ++mt)
            acc[t][mt] = (f32x4){0.f, 0.f, 0.f, 0.f};

    for (int c = 0; c < 10; ++c) {
        short8 a[2];
        #pragma unroll
        for (int mt = 0; mt < 2; ++mt)
            a[mt] = *(const short8*)&At[(mt * 16 + m) * ATS + c * 32 + quad * 8];
        #pragma unroll
        for (int t = 0; t < 5; ++t) {
            short8 b = *(const short8*)(wfrag_l
                + ((size_t)(c * NTILES + nt0 + t) * 64 + lane) * 8);
            #pragma unroll
            for (int mt = 0; mt < 2; ++mt)
                acc[t][mt] = __builtin_amdgcn_mfma_f32_16x16x32_bf16(
                    a[mt], b, acc[t][mt], 0, 0, 0);
        }
    }
    #pragma unroll
    for (int t = 0; t < 5; ++t) {
        int col = (nt0 + t) * 16 + m;
        if (col >= HID) continue;
        #pragma unroll
        for (int mt = 0; mt < 2; ++mt) {
            long rbase = (e0 + mt * 16 + quad * 4) * HP + col;
            #pragma unroll
            for (int r = 0; r < 4; ++r)
                h[rbase + (long)r * HP] = f2bf(acc[t][mt][r]);
        }
    }
}

// Final edge update (no gemm after): phase-0 P via MFMA, then in-place update.
__global__ __launch_bounds__(256) void edge_update_mfma(
    ushort_t* h, const ushort_t* __restrict__ Sb,
    const ushort_t* __restrict__ xW1b, const float* __restrict__ edge_attr,
    const int* __restrict__ row, const ushort_t* __restrict__ w2frag)
{
    __shared__ ushort_t Pt[32 * ATS];
    __shared__ int rows[32];
    const int tid = threadIdx.x;
    const int wave = tid >> 6, lane = tid & 63;
    const int quad = lane >> 4, m = lane & 15;
    const long e0 = (long)blockIdx.x * 32;
    if (tid < 32) rows[tid] = row[e0 + tid];

    {
        short8 a_ea[2];
        #pragma unroll
        for (int mt = 0; mt < 2; ++mt) {
            union { uint4 u4; short8 s8; } af;
            if (quad < 2) {
                const float* eap = edge_attr + (e0 + mt * 16 + m) * 16 + quad * 8;
                float4 v0 = *(const float4*)eap;
                float4 v1 = *(const float4*)(eap + 4);
                af.u4.x = fpack(v0.x, v0.y); af.u4.y = fpack(v0.z, v0.w);
                af.u4.z = fpack(v1.x, v1.y); af.u4.w = fpack(v1.z, v1.w);
            } else {
                af.u4.x = 0; af.u4.y = 0; af.u4.z = 0; af.u4.w = 0;
            }
            a_ea[mt] = af.s8;
        }
        const int nt0 = wave * 5;
        #pragma unroll
        for (int t = 0; t < 5; ++t) {
            short8 b = *(const short8*)(w2frag + ((size_t)(nt0 + t) * 64 + lane) * 8);
            #pragma unroll
            for (int mt = 0; mt < 2; ++mt) {
                f32x4 pc = (f32x4){0.f, 0.f, 0.f, 0.f};
                pc = __builtin_amdgcn_mfma_f32_16x16x32_bf16(a_ea[mt], b, pc, 0, 0, 0);
                int c = (nt0 + t) * 16 + m;
                #pragma unroll
                for (int r = 0; r < 4; ++r)
                    Pt[(mt * 16 + quad * 4 + r) * ATS + c] = f2bf(pc[r]);
            }
        }
    }
    __syncthreads();

    for (int i = tid; i < 16 * 75; i += 256) {
        int p = i / 75, g = i % 75;
        int c0 = 4 * g;
        int la = 2 * p, lb = 2 * p + 1;
        long Ea = e0 + la, Eb = e0 + lb;
        int ra = rows[la], rb = rows[lb];
        ushort4 wa = *(const ushort4*)&h[Ea * HP + c0];
        ushort4 wb = *(const ushort4*)&h[Eb * HP + c0];
        ushort4 sa = *(const ushort4*)&Sb[(long)ra * HID + c0];
        ushort4 sb = *(const ushort4*)&Sb[(long)rb * HID + c0];
        ushort4 xa = *(const ushort4*)&xW1b[(long)ra * HID + c0];
        ushort4 xb = *(const ushort4*)&xW1b[(long)rb * HID + c0];
        ushort4 pa = *(const ushort4*)&Pt[la * ATS + c0];
        ushort4 pb = *(const ushort4*)&Pt[lb * ATS + c0];
        float h0a[4], h0b[4];
        h0a[0] = fmaxf(bf2f(xa.x) + bf2f(pa.x), 0.f);
        h0a[1] = fmaxf(bf2f(xa.y) + bf2f(pa.y), 0.f);
        h0a[2] = fmaxf(bf2f(xa.z) + bf2f(pa.z), 0.f);
        h0a[3] = fmaxf(bf2f(xa.w) + bf2f(pa.w), 0.f);
        h0b[0] = fmaxf(bf2f(xb.x) + bf2f(pb.x), 0.f);
        h0b[1] = fmaxf(bf2f(xb.y) + bf2f(pb.y), 0.f);
        h0b[2] = fmaxf(bf2f(xb.z) + bf2f(pb.z), 0.f);
        h0b[3] = fmaxf(bf2f(xb.w) + bf2f(pb.w), 0.f);
        ushort4 ova, ovb;
        ova.x = f2bf(fmaxf(bf2f(sa.x) - bf2f(wb.x) + h0a[0], 0.f));
        ova.y = f2bf(fmaxf(bf2f(sa.y) - bf2f(wb.y) + h0a[1], 0.f));
        ova.z = f2bf(fmaxf(bf2f(sa.z) - bf2f(wb.z) + h0a[2], 0.f));
        ova.w = f2bf(fmaxf(bf2f(sa.w) - bf2f(wb.w) + h0a[3], 0.f));
        ovb.x = f2bf(fmaxf(bf2f(sb.x) - bf2f(wa.x) + h0b[0], 0.f));
        ovb.y = f2bf(fmaxf(bf2f(sb.y) - bf2f(wa.y) + h0b[1], 0.f));
        ovb.z = f2bf(fmaxf(bf2f(sb.z) - bf2f(wa.z) + h0b[2], 0.f));
        ovb.w = f2bf(fmaxf(bf2f(sb.w) - bf2f(wa.w) + h0b[3], 0.f));
        ((ushort4*)h)[Ea * (HP / 4) + g] = ova;
        ((ushort4*)h)[Eb * (HP / 4) + g] = ovb;
    }
}

// K4: Sb[n][:] = bf16( bias[:] + segsum );  stride HID
__global__ __launch_bounds__(256) void gather_sum(
    const ushort_t* __restrict__ src, const int* __restrict__ offsets,
    const int* __restrict__ ends, const int* __restrict__ eid,
    const float* __restrict__ bias, ushort_t* __restrict__ Sb)
{
    long idx = (long)blockIdx.x * 256 + threadIdx.x;
    if (idx >= (long)N_NODES * 75) return;
    int n = (int)(idx / 75);
    int g = (int)(idx % 75);
    int beg = offsets[n], end = ends[n];
    float a0 = 0.f, a1 = 0.f, a2 = 0.f, a3 = 0.f;
    float b0 = 0.f, b1 = 0.f, b2 = 0.f, b3 = 0.f;
    int j = beg;
    for (; j + 1 < end; j += 2) {
        int e0i = eid[j], e1i = eid[j + 1];
        ushort4 v0 = ((const ushort4*)src)[(long)e0i * (HP / 4) + g];
        ushort4 v1 = ((const ushort4*)src)[(long)e1i * (HP / 4) + g];
        a0 += bf2f(v0.x); a1 += bf2f(v0.y); a2 += bf2f(v0.z); a3 += bf2f(v0.w);
        b0 += bf2f(v1.x); b1 += bf2f(v1.y); b2 += bf2f(v1.z); b3 += bf2f(v1.w);
    }
    if (j < end) {
        int e0i = eid[j];
        ushort4 v0 = ((const ushort4*)src)[(long)e0i * (HP / 4) + g];
        a0 += bf2f(v0.x); a1 += bf2f(v0.y); a2 += bf2f(v0.z); a3 += bf2f(v0.w);
    }
    float4 bv = *(const float4*)&bias[4 * g];
    ushort4 o;
    o.x = f2bf(a0 + b0 + bv.x); o.y = f2bf(a1 + b1 + bv.y);
    o.z = f2bf(a2 + b2 + bv.z); o.w = f2bf(a3 + b3 + bv.w);
    *(ushort4*)&Sb[(long)n * HID + 4 * g] = o;
}

// K4b: final gather -> bf16 into Ab cols 64..363
__global__ __launch_bounds__(256) void gather_ab(
    const ushort_t* __restrict__ src, const int* __restrict__ offsets,
    const int* __restrict__ ends, const int* __restrict__ eid,
    ushort_t* __restrict__ Ab)
{
    long idx = (long)blockIdx.x * 256 + threadIdx.x;
    if (idx >= (long)N_NODES * 75) return;
    int n = (int)(idx / 75);
    int g = (int)(idx % 75);
    int beg = offsets[n], end = ends[n];
    float a0 = 0.f, a1 = 0.f, a2 = 0.f, a3 = 0.f;
    float b0 = 0.f, b1 = 0.f, b2 = 0.f, b3 = 0.f;
    int j = beg;
    for (; j + 1 < end; j += 2) {
        int e0i = eid[j], e1i = eid[j + 1];
        ushort4 v0 = ((const ushort4*)src)[(long)e0i * (HP / 4) + g];
        ushort4 v1 = ((const ushort4*)src)[(long)e1i * (HP / 4) + g];
        a0 += bf2f(v0.x); a1 += bf2f(v0.y); a2 += bf2f(v0.z); a3 += bf2f(v0.w);
        b0 += bf2f(v1.x); b1 += bf2f(v1.y); b2 += bf2f(v1.z); b3 += bf2f(v1.w);
    }
    if (j < end) {
        int e0i = eid[j];
        ushort4 v0 = ((const ushort4*)src)[(long)e0i * (HP / 4) + g];
        a0 += bf2f(v0.x); a1 += bf2f(v0.y); a2 += bf2f(v0.z); a3 += bf2f(v0.w);
    }
    ushort4 o;
    o.x = f2bf(a0 + b0); o.y = f2bf(a1 + b1);
    o.z = f2bf(a2 + b2); o.w = f2bf(a3 + b3);
    *(ushort4*)&Ab[(long)n * KE2N + 64 + 4 * g] = o;
}

__global__ __launch_bounds__(256) void x_fill(
    const float* __restrict__ x, ushort_t* __restrict__ Ab)
{
    long idx = (long)blockIdx.x * 256 + threadIdx.x;
    if (idx >= (long)N_NODES * 21) return;
    int n = (int)(idx / 21);
    int q = (int)(idx % 21);
    ushort4 o;
    if (q < 16) {
        float4 v = *(const float4*)&x[(long)n * 64 + 4 * q];
        o.x = f2bf(v.x); o.y = f2bf(v.y); o.z = f2bf(v.z); o.w = f2bf(v.w);
        *(ushort4*)&Ab[(long)n * KE2N + 4 * q] = o;
    } else {
        o.x = 0; o.y = 0; o.z = 0; o.w = 0;
        *(ushort4*)&Ab[(long)n * KE2N + 364 + 4 * (q - 16)] = o;
    }
}

// K7: hn = relu(Ab @ W_e2n + b)
__global__ __launch_bounds__(256) void e2n_mfma(
    const ushort_t* __restrict__ Ab, const ushort_t* __restrict__ wfrag2,
    const float* __restrict__ b_e2n, float* __restrict__ hn)
{
    const int tid = threadIdx.x;
    const int wave = tid >> 6, lane = tid & 63;
    const int quad = lane >> 4, m = lane & 15;
    const long n0 = (long)blockIdx.x * 64;
    const int nt0 = wave * 5;

    f32x4 acc[5][4];
    #pragma unroll
    for (int t = 0; t < 5; ++t)
        #pragma unroll
        for (int mt = 0; mt < 4; ++mt)
            acc[t][mt] = (f32x4){0.f, 0.f, 0.f, 0.f};

    for (int c = 0; c < 12; ++c) {
        short8 a[4];
        #pragma unroll
        for (int mt = 0; mt < 4; ++mt) {
            long r = n0 + mt * 16 + m;
            if (r > N_NODES - 1) r = N_NODES - 1;
            a[mt] = *(const short8*)(Ab + r * KE2N + c * 32 + quad * 8);
        }
        #pragma unroll
        for (int t = 0; t < 5; ++t) {
            short8 b = *(const short8*)(wfrag2
                + ((size_t)(c * NTILES + nt0 + t) * 64 + lane) * 8);
            #pragma unroll
            for (int mt = 0; mt < 4; ++mt)
                acc[t][mt] = __builtin_amdgcn_mfma_f32_16x16x32_bf16(
                    a[mt], b, acc[t][mt], 0, 0, 0);
        }
    }

    #pragma unroll
    for (int t = 0; t < 5; ++t) {
        int col = (nt0 + t) * 16 + m;
        if (col >= HID) continue;
        float bias = b_e2n[col];
        #pragma unroll
        for (int mt = 0; mt < 4; ++mt) {
            long rw = n0 + mt * 16 + quad * 4;
            #pragma unroll
            for (int r = 0; r < 4; ++r) {
                long rowi = rw + r;
                if (rowi < N_NODES)
                    hn[rowi * HP + col] = fmaxf(acc[t][mt][r] + bias, 0.f);
            }
        }
    }
}

__global__ __launch_bounds__(256) void pool_graph(
    const float* __restrict__ hn, const int* __restrict__ goff,
    float* __restrict__ pooled)
{
    int g = blockIdx.x;
    int beg = goff[g], end = goff[g + 1];
    for (int c = threadIdx.x; c < HID; c += 256) {
        float acc = 0.f;
        for (int n = beg; n < end; ++n)
            acc += hn[(long)n * HP + c];
        pooled[(long)g * HID + c] = acc;
    }
}

__global__ __launch_bounds__(64) void ffn_out(
    const float* __restrict__ pooled, const float* __restrict__ W_ffn,
    const float* __restrict__ b_ffn, float* __restrict__ out)
{
    int g = blockIdx.x;
    int lane = threadIdx.x;
    float s = 0.f;
    for (int c = lane; c < HID; c += 64)
        s += pooled[(long)g * HID + c] * W_ffn[c];
    #pragma unroll
    for (int off = 32; off > 0; off >>= 1)
        s += __shfl_down(s, off, 64);
    if (lane == 0) out[g] = s + b_ffn[0];
}

extern "C" void kernel_launch(void* const* d_in, const int* in_sizes, int n_in,
                              void* d_out, int out_size, void* d_ws, size_t ws_size,
                              hipStream_t stream) {
    const float* x         = (const float*)d_in[0];
    const float* edge_attr = (const float*)d_in[1];
    const int*   edge_index= (const int*)d_in[2];
    const int*   batch     = (const int*)d_in[3];
    const float* W_init    = (const float*)d_in[4];
    const float* b_init    = (const float*)d_in[5];
    const float* W_convs   = (const float*)d_in[6];
    const float* b_convs   = (const float*)d_in[7];
    const float* W_e2n     = (const float*)d_in[8];
    const float* b_e2n     = (const float*)d_in[9];
    const float* W_ffn     = (const float*)d_in[10];
    const float* b_ffn     = (const float*)d_in[11];
    float* out = (float*)d_out;

    const int* row = edge_index;
    const int* col = edge_index + N_EDGES;
    const float* W2 = W_init + (size_t)F_NODE * HID;

    // Workspace (~236 MB) — ws known in [255, 440) MB from R12, fits.
    const size_t need = (size_t)N_EDGES * HP * 2              // h 204.8M
                      + (size_t)N_NODES * HID * 2             // Sb 12M
                      + (size_t)N_NODES * KE2N * 2            // Ab 15.36M (xW1b alias)
                      + (size_t)N_GRAPHS * HID * 4
                      + (size_t)N_NODES * 4 * 2 + (size_t)N_EDGES * 4
                      + (size_t)DEPTH * WFRAG_USHORT_PER_LAYER * 2
                      + (size_t)WE2NFRAG_USHORT * 2
                      + (size_t)W2FRAG_USHORT * 2
                      + (size_t)(N_GRAPHS + 1 + N_GRAPHS) * 4 + 32768;
    if (ws_size < need) return;  // clean absmax fail, not a crash

    char* p = (char*)d_ws;
    auto take = [&](size_t bytes) {
        char* q = p;
        p += (bytes + 255) & ~(size_t)255;
        return q;
    };
    ushort_t* h       = (ushort_t*)take((size_t)N_EDGES * HP * 2);
    ushort_t* Sb      = (ushort_t*)take((size_t)N_NODES * HID * 2);
    ushort_t* Ab      = (ushort_t*)take((size_t)N_NODES * KE2N * 2);
    float*    pooled  = (float*)take((size_t)N_GRAPHS * HID * 4);
    int*      cursor  = (int*)take((size_t)N_NODES * 4);
    int*      offsets = (int*)take((size_t)N_NODES * 4);
    int*      eid     = (int*)take((size_t)N_EDGES * 4);
    ushort_t* wfrag   = (ushort_t*)take((size_t)DEPTH * WFRAG_USHORT_PER_LAYER * 2);
    ushort_t* wfrag2  = (ushort_t*)take((size_t)WE2NFRAG_USHORT * 2);
    ushort_t* w2frag  = (ushort_t*)take((size_t)W2FRAG_USHORT * 2);
    int*      gdeg    = (int*)take((size_t)N_GRAPHS * 4);
    int*      goff    = (int*)take((size_t)(N_GRAPHS + 1) * 4);

    ushort_t* xW1b = Ab;        // alias: xW1b dead before x_fill writes Ab
    float*    hn   = (float*)h; // alias: h dead after gather_ab

    // CSR + graph-offset build
    hipMemsetAsync(cursor, 0, (size_t)N_NODES * 4, stream);
    hipMemsetAsync(gdeg, 0, (size_t)N_GRAPHS * 4, stream);
    csr_hist<<<N_EDGES / 256, 256, 0, stream>>>(col, cursor);
    csr_scan<<<1, 256, 0, stream>>>(cursor, offsets, cursor);
    csr_fill<<<N_EDGES / 256, 256, 0, stream>>>(col, cursor, eid);
    ghist<<<(N_NODES + 255) / 256, 256, 0, stream>>>(batch, gdeg);
    gscan<<<1, 128, 0, stream>>>(gdeg, goff);

    wfrag_build<<<dim3(10, NTILES, DEPTH), 64, 0, stream>>>(W_convs, wfrag);
    wfrag2_build<<<dim3(12, NTILES, 1), 64, 0, stream>>>(W_e2n, wfrag2);
    w2frag_build<<<NTILES, 64, 0, stream>>>(W2, w2frag);

    node_init_gemm<<<N_NODES / 16, 256, 0, stream>>>(x, W_init, b_init, xW1b);

    const int GS_GRID = ((N_NODES * 75) + 255) / 256;

    // layer 0
    fused_conv<false><<<N_EDGES / 32, 256, 0, stream>>>(
        h, Sb, xW1b, edge_attr, row, w2frag, wfrag);
    gather_sum<<<GS_GRID, 256, 0, stream>>>(
        h, offsets, cursor, eid, b_convs + 0 * HID, Sb);
    // layers 1,2
    fused_conv<true><<<N_EDGES / 32, 256, 0, stream>>>(
        h, Sb, xW1b, edge_attr, row, w2frag,
        wfrag + 1 * (size_t)WFRAG_USHORT_PER_LAYER);
    gather_sum<<<GS_GRID, 256, 0, stream>>>(
        h, offsets, cursor, eid, b_convs + 1 * HID, Sb);
    fused_conv<true><<<N_EDGES / 32, 256, 0, stream>>>(
        h, Sb, xW1b, edge_attr, row, w2frag,
        wfrag + 2 * (size_t)WFRAG_USHORT_PER_LAYER);
    gather_sum<<<GS_GRID, 256, 0, stream>>>(
        h, offsets, cursor, eid, b_convs + 2 * HID, Sb);
    // final update
    edge_update_mfma<<<N_EDGES / 32, 256, 0, stream>>>(
        h, Sb, xW1b, edge_attr, row, w2frag);

    // ---- e2n path ----
    x_fill<<<((N_NODES * 21) + 255) / 256, 256, 0, stream>>>(x, Ab);
    gather_ab<<<GS_GRID, 256, 0, stream>>>(h, offsets, cursor, eid, Ab);
    e2n_mfma<<<(N_NODES + 63) / 64, 256, 0, stream>>>(Ab, wfrag2, b_e2n, hn);
    pool_graph<<<N_GRAPHS, 256, 0, stream>>>(hn, goff, pooled);
    ffn_out<<<N_GRAPHS, 64, 0, stream>>>(pooled, W_ffn, b_ffn, out);
}

// Round 14
// 1244.140 us; speedup vs baseline: 1.8550x; 1.0116x over previous
//
#include <hip/hip_runtime.h>
#include <hip/hip_bf16.h>

typedef unsigned short ushort_t;
typedef __attribute__((ext_vector_type(8))) short short8;   // 8 bf16 = 4 VGPRs
typedef __attribute__((ext_vector_type(4))) float f32x4;    // MFMA C/D

#define N_NODES 20000
#define N_EDGES 320000
#define F_NODE 64
#define F_EDGE 16
#define HID 300
#define HP 320          // padded hidden: row stride of h
#define NTILES 20       // wfrag n-tiles; tile 19 pure pad
#define DEPTH 3
#define N_GRAPHS 128
#define KE2N 384        // e2n K: 64 (x) + 300 (S) + 20 pad
#define ATS 328         // LDS A-tile row stride (ushorts)

#define WFRAG_USHORT_PER_LAYER (10 * NTILES * 64 * 8)  // 102400 ushorts
#define W2FRAG_USHORT (NTILES * 64 * 8)                // 10240 ushorts (1 K-chunk)
#define WE2NFRAG_USHORT (12 * NTILES * 64 * 8)         // 122880 ushorts

__device__ __forceinline__ float bf2f(ushort_t u) {
    union { unsigned int i; float f; } v;
    v.i = ((unsigned int)u) << 16;
    return v.f;
}

// Packed f32x2 -> bf16x2. gfx950 HW instruction if available (1 VALU op for
// 2 values vs ~10 for the bit-trick); RNA 2-op fallback otherwise.
__device__ __forceinline__ unsigned int fpack(float lo, float hi) {
#if __has_builtin(__builtin_amdgcn_cvt_pk_bf16_f32)
    auto r = __builtin_amdgcn_cvt_pk_bf16_f32(lo, hi);
    union { decltype(r) b; unsigned int u; } v;
    v.b = r;
    return v.u;
#else
    union { float f; unsigned int i; } a, b;
    a.f = lo; b.f = hi;
    return ((a.i + 0x8000u) >> 16) | ((b.i + 0x8000u) & 0xffff0000u);
#endif
}
__device__ __forceinline__ ushort_t f2bf(float f) {
    return (ushort_t)(fpack(f, 0.f) & 0xffffu);
}

// ---------------- CSR build ----------------
__global__ __launch_bounds__(256) void csr_hist(
    const int* __restrict__ col, int* __restrict__ deg)
{
    int e = blockIdx.x * 256 + threadIdx.x;
    atomicAdd(&deg[col[e]], 1);
}

__global__ __launch_bounds__(256) void csr_scan(
    const int* __restrict__ deg, int* __restrict__ offsets,
    int* __restrict__ cursor)
{
    __shared__ int sums[256];
    const int t = threadIdx.x;
    const int CH = 79;
    int base = t * CH;
    int local = 0;
    for (int i = 0; i < CH; ++i) {
        int idx = base + i;
        if (idx < N_NODES) local += deg[idx];
    }
    sums[t] = local;
    __syncthreads();
    for (int off = 1; off < 256; off <<= 1) {
        int v = (t >= off) ? sums[t - off] : 0;
        __syncthreads();
        sums[t] += v;
        __syncthreads();
    }
    int run = (t > 0) ? sums[t - 1] : 0;
    for (int i = 0; i < CH; ++i) {
        int idx = base + i;
        if (idx < N_NODES) {
            offsets[idx] = run;
            cursor[idx] = run;
            run += deg[idx];
        }
    }
}

__global__ __launch_bounds__(256) void csr_fill(
    const int* __restrict__ col, int* __restrict__ cursor,
    int* __restrict__ eid)
{
    int e = blockIdx.x * 256 + threadIdx.x;
    int pos = atomicAdd(&cursor[col[e]], 1);
    eid[pos] = e;
}

__global__ __launch_bounds__(256) void ghist(
    const int* __restrict__ batch, int* __restrict__ gdeg)
{
    int n = blockIdx.x * 256 + threadIdx.x;
    if (n < N_NODES) atomicAdd(&gdeg[batch[n]], 1);
}

__global__ __launch_bounds__(128) void gscan(
    const int* __restrict__ gdeg, int* __restrict__ goff)
{
    __shared__ int s[128];
    int t = threadIdx.x;
    int d = gdeg[t];
    s[t] = d;
    __syncthreads();
    for (int off = 1; off < 128; off <<= 1) {
        int v = (t >= off) ? s[t - off] : 0;
        __syncthreads();
        s[t] += v;
        __syncthreads();
    }
    goff[t] = s[t] - d;
    if (t == 127) goff[128] = s[127];
}

// ---------------- W fragment pre-packs ----------------
__global__ __launch_bounds__(64) void wfrag_build(
    const float* __restrict__ W_convs, ushort_t* __restrict__ wfrag)
{
    const int c = blockIdx.x, t = blockIdx.y, l = blockIdx.z;
    const int lane = threadIdx.x;
    const int k0 = c * 32 + (lane >> 4) * 8;
    const int n  = t * 16 + (lane & 15);
    ushort_t* dst = wfrag + (size_t)l * WFRAG_USHORT_PER_LAYER
                  + ((size_t)(c * NTILES + t) * 64 + lane) * 8;
    const float* Wl = W_convs + (size_t)l * HID * HID;
    #pragma unroll
    for (int j = 0; j < 8; ++j) {
        int k = k0 + j;
        float v = (k < HID && n < HID) ? Wl[(long)k * HID + n] : 0.f;
        dst[j] = f2bf(v);
    }
}

__global__ __launch_bounds__(64) void wfrag2_build(
    const float* __restrict__ W_e2n, ushort_t* __restrict__ wfrag2)
{
    const int c = blockIdx.x, t = blockIdx.y;
    const int lane = threadIdx.x;
    const int k0 = c * 32 + (lane >> 4) * 8;
    const int n  = t * 16 + (lane & 15);
    ushort_t* dst = wfrag2 + ((size_t)(c * NTILES + t) * 64 + lane) * 8;
    #pragma unroll
    for (int j = 0; j < 8; ++j) {
        int k = k0 + j;
        float v = (k < F_NODE + HID && n < HID) ? W_e2n[(long)k * HID + n] : 0.f;
        dst[j] = f2bf(v);
    }
}

// W2 (= W_init rows 64..79) as ONE 16x16x32 B-chunk
__global__ __launch_bounds__(64) void w2frag_build(
    const float* __restrict__ W2, ushort_t* __restrict__ w2frag)
{
    const int t = blockIdx.x;
    const int lane = threadIdx.x;
    const int k0 = (lane >> 4) * 8;
    const int n  = t * 16 + (lane & 15);
    ushort_t* dst = w2frag + ((size_t)t * 64 + lane) * 8;
    #pragma unroll
    for (int j = 0; j < 8; ++j) {
        int k = k0 + j;
        float v = (k < F_EDGE && n < HID) ? W2[(long)k * HID + n] : 0.f;
        dst[j] = f2bf(v);
    }
}

// ---------------- kernels ----------------

// K1: xW1b[n][c] = bf16(b_init[c] + x[n] @ W_init[0:64]);  stride HID
__global__ __launch_bounds__(256) void node_init_gemm(
    const float* __restrict__ x, const float* __restrict__ W_init,
    const float* __restrict__ b_init, ushort_t* __restrict__ xW1b)
{
    __shared__ float xs[16 * 64];
    const int tid = threadIdx.x;
    const long n0 = (long)blockIdx.x * 16;
    for (int i = tid; i < 16 * 64; i += 256) xs[i] = x[n0 * 64 + i];
    __syncthreads();
    const int nl = tid >> 4, ct = tid & 15;
    for (int q = 0; q < 19; ++q) {
        int c = ct + 16 * q;
        if (c < HID) {
            float acc = b_init[c];
            #pragma unroll 8
            for (int k = 0; k < 64; ++k)
                acc = fmaf(xs[nl * 64 + k], W_init[(long)k * HID + c], acc);
            xW1b[(n0 + nl) * HID + c] = f2bf(acc);
        }
    }
}

// Fused conv layer, 32-edge blocks, 256 thr / 4 waves.
// phase 0: P = ea_tile @ W2 via MFMA -> LDS At.
// phase 1: edge update into At (pure loads + pk-cvt packing).
// phase 2: main MFMA h = A @ Wl (acc[5][2]).
template<bool UPDATE>
__global__ __launch_bounds__(256) void fused_conv(
    ushort_t* h, const ushort_t* __restrict__ Sb,
    const ushort_t* __restrict__ xW1b, const float* __restrict__ edge_attr,
    const int* __restrict__ row, const ushort_t* __restrict__ w2frag,
    const ushort_t* __restrict__ wfrag_l)
{
    __shared__ ushort_t At[32 * ATS];   // 20992 B
    __shared__ int rows[32];
    const int tid = threadIdx.x;
    const int wave = tid >> 6, lane = tid & 63;
    const int quad = lane >> 4, m = lane & 15;
    const long e0 = (long)blockIdx.x * 32;
    if (tid < 32) rows[tid] = row[e0 + tid];

    // ---- phase 0: P = EA @ W2 ----
    {
        short8 a_ea[2];
        #pragma unroll
        for (int mt = 0; mt < 2; ++mt) {
            union { uint4 u4; short8 s8; } af;
            if (quad < 2) {
                const float* eap = edge_attr + (e0 + mt * 16 + m) * 16 + quad * 8;
                float4 v0 = *(const float4*)eap;
                float4 v1 = *(const float4*)(eap + 4);
                af.u4.x = fpack(v0.x, v0.y); af.u4.y = fpack(v0.z, v0.w);
                af.u4.z = fpack(v1.x, v1.y); af.u4.w = fpack(v1.z, v1.w);
            } else {
                af.u4.x = 0; af.u4.y = 0; af.u4.z = 0; af.u4.w = 0;
            }
            a_ea[mt] = af.s8;
        }
        const int nt0 = wave * 5;
        #pragma unroll
        for (int t = 0; t < 5; ++t) {
            short8 b = *(const short8*)(w2frag + ((size_t)(nt0 + t) * 64 + lane) * 8);
            #pragma unroll
            for (int mt = 0; mt < 2; ++mt) {
                f32x4 pc = (f32x4){0.f, 0.f, 0.f, 0.f};
                pc = __builtin_amdgcn_mfma_f32_16x16x32_bf16(a_ea[mt], b, pc, 0, 0, 0);
                int c = (nt0 + t) * 16 + m;
                #pragma unroll
                for (int r = 0; r < 4; ++r)
                    At[(mt * 16 + quad * 4 + r) * ATS + c] = f2bf(pc[r]);
            }
        }
    }
    __syncthreads();   // P complete (+ rows)

    // ---- phase 1: edge update into At ----
    for (int i = tid; i < 16 * 80; i += 256) {
        int p = i / 80, g = i % 80;
        int c0 = 4 * g;
        int la = 2 * p, lb = 2 * p + 1;
        uint2 oa, ob;
        if (g < 75) {
            long Ea = e0 + la, Eb = e0 + lb;
            int ra = rows[la], rb = rows[lb];
            ushort4 xa = *(const ushort4*)&xW1b[(long)ra * HID + c0];
            ushort4 xb = *(const ushort4*)&xW1b[(long)rb * HID + c0];
            ushort4 pa = *(const ushort4*)&At[la * ATS + c0];
            ushort4 pb = *(const ushort4*)&At[lb * ATS + c0];
            float h0a[4], h0b[4];
            h0a[0] = fmaxf(bf2f(xa.x) + bf2f(pa.x), 0.f);
            h0a[1] = fmaxf(bf2f(xa.y) + bf2f(pa.y), 0.f);
            h0a[2] = fmaxf(bf2f(xa.z) + bf2f(pa.z), 0.f);
            h0a[3] = fmaxf(bf2f(xa.w) + bf2f(pa.w), 0.f);
            h0b[0] = fmaxf(bf2f(xb.x) + bf2f(pb.x), 0.f);
            h0b[1] = fmaxf(bf2f(xb.y) + bf2f(pb.y), 0.f);
            h0b[2] = fmaxf(bf2f(xb.z) + bf2f(pb.z), 0.f);
            h0b[3] = fmaxf(bf2f(xb.w) + bf2f(pb.w), 0.f);
            if (UPDATE) {
                ushort4 wa = *(const ushort4*)&h[Ea * HP + c0];
                ushort4 wb = *(const ushort4*)&h[Eb * HP + c0];
                ushort4 sa = *(const ushort4*)&Sb[(long)ra * HID + c0];
                ushort4 sb = *(const ushort4*)&Sb[(long)rb * HID + c0];
                oa.x = fpack(fmaxf(bf2f(sa.x) - bf2f(wb.x) + h0a[0], 0.f),
                             fmaxf(bf2f(sa.y) - bf2f(wb.y) + h0a[1], 0.f));
                oa.y = fpack(fmaxf(bf2f(sa.z) - bf2f(wb.z) + h0a[2], 0.f),
                             fmaxf(bf2f(sa.w) - bf2f(wb.w) + h0a[3], 0.f));
                ob.x = fpack(fmaxf(bf2f(sb.x) - bf2f(wa.x) + h0b[0], 0.f),
                             fmaxf(bf2f(sb.y) - bf2f(wa.y) + h0b[1], 0.f));
                ob.y = fpack(fmaxf(bf2f(sb.z) - bf2f(wa.z) + h0b[2], 0.f),
                             fmaxf(bf2f(sb.w) - bf2f(wa.w) + h0b[3], 0.f));
            } else {
                oa.x = fpack(h0a[0], h0a[1]); oa.y = fpack(h0a[2], h0a[3]);
                ob.x = fpack(h0b[0], h0b[1]); ob.y = fpack(h0b[2], h0b[3]);
            }
        } else {
            oa.x = 0; oa.y = 0;   // K-pad cols 300..319
            ob = oa;
        }
        *(uint2*)&At[la * ATS + c0] = oa;
        *(uint2*)&At[lb * ATS + c0] = ob;
    }
    __syncthreads();   // A tile complete; all h reads done

    // ---- phase 2: main MFMA ----
    const int nt0 = wave * 5;
    f32x4 acc[5][2];
    #pragma unroll
    for (int t = 0; t < 5; ++t)
        #pragma unroll
        for (int mt = 0; mt < 2; ++mt)
            acc[t][mt] = (f32x4){0.f, 0.f, 0.f, 0.f};

    for (int c = 0; c < 10; ++c) {
        short8 a[2];
        #pragma unroll
        for (int mt = 0; mt < 2; ++mt)
            a[mt] = *(const short8*)&At[(mt * 16 + m) * ATS + c * 32 + quad * 8];
        #pragma unroll
        for (int t = 0; t < 5; ++t) {
            short8 b = *(const short8*)(wfrag_l
                + ((size_t)(c * NTILES + nt0 + t) * 64 + lane) * 8);
            #pragma unroll
            for (int mt = 0; mt < 2; ++mt)
                acc[t][mt] = __builtin_amdgcn_mfma_f32_16x16x32_bf16(
                    a[mt], b, acc[t][mt], 0, 0, 0);
        }
    }
    #pragma unroll
    for (int t = 0; t < 5; ++t) {
        int col = (nt0 + t) * 16 + m;
        if (col >= HID) continue;
        #pragma unroll
        for (int mt = 0; mt < 2; ++mt) {
            long rbase = (e0 + mt * 16 + quad * 4) * HP + col;
            #pragma unroll
            for (int r = 0; r < 4; ++r)
                h[rbase + (long)r * HP] = f2bf(acc[t][mt][r]);
        }
    }
}

// Final edge update: phase-0 P via MFMA, then in-place update.
__global__ __launch_bounds__(256) void edge_update_mfma(
    ushort_t* h, const ushort_t* __restrict__ Sb,
    const ushort_t* __restrict__ xW1b, const float* __restrict__ edge_attr,
    const int* __restrict__ row, const ushort_t* __restrict__ w2frag)
{
    __shared__ ushort_t Pt[32 * ATS];
    __shared__ int rows[32];
    const int tid = threadIdx.x;
    const int wave = tid >> 6, lane = tid & 63;
    const int quad = lane >> 4, m = lane & 15;
    const long e0 = (long)blockIdx.x * 32;
    if (tid < 32) rows[tid] = row[e0 + tid];

    {
        short8 a_ea[2];
        #pragma unroll
        for (int mt = 0; mt < 2; ++mt) {
            union { uint4 u4; short8 s8; } af;
            if (quad < 2) {
                const float* eap = edge_attr + (e0 + mt * 16 + m) * 16 + quad * 8;
                float4 v0 = *(const float4*)eap;
                float4 v1 = *(const float4*)(eap + 4);
                af.u4.x = fpack(v0.x, v0.y); af.u4.y = fpack(v0.z, v0.w);
                af.u4.z = fpack(v1.x, v1.y); af.u4.w = fpack(v1.z, v1.w);
            } else {
                af.u4.x = 0; af.u4.y = 0; af.u4.z = 0; af.u4.w = 0;
            }
            a_ea[mt] = af.s8;
        }
        const int nt0 = wave * 5;
        #pragma unroll
        for (int t = 0; t < 5; ++t) {
            short8 b = *(const short8*)(w2frag + ((size_t)(nt0 + t) * 64 + lane) * 8);
            #pragma unroll
            for (int mt = 0; mt < 2; ++mt) {
                f32x4 pc = (f32x4){0.f, 0.f, 0.f, 0.f};
                pc = __builtin_amdgcn_mfma_f32_16x16x32_bf16(a_ea[mt], b, pc, 0, 0, 0);
                int c = (nt0 + t) * 16 + m;
                #pragma unroll
                for (int r = 0; r < 4; ++r)
                    Pt[(mt * 16 + quad * 4 + r) * ATS + c] = f2bf(pc[r]);
            }
        }
    }
    __syncthreads();

    for (int i = tid; i < 16 * 75; i += 256) {
        int p = i / 75, g = i % 75;
        int c0 = 4 * g;
        int la = 2 * p, lb = 2 * p + 1;
        long Ea = e0 + la, Eb = e0 + lb;
        int ra = rows[la], rb = rows[lb];
        ushort4 wa = *(const ushort4*)&h[Ea * HP + c0];
        ushort4 wb = *(const ushort4*)&h[Eb * HP + c0];
        ushort4 sa = *(const ushort4*)&Sb[(long)ra * HID + c0];
        ushort4 sb = *(const ushort4*)&Sb[(long)rb * HID + c0];
        ushort4 xa = *(const ushort4*)&xW1b[(long)ra * HID + c0];
        ushort4 xb = *(const ushort4*)&xW1b[(long)rb * HID + c0];
        ushort4 pa = *(const ushort4*)&Pt[la * ATS + c0];
        ushort4 pb = *(const ushort4*)&Pt[lb * ATS + c0];
        float h0a[4], h0b[4];
        h0a[0] = fmaxf(bf2f(xa.x) + bf2f(pa.x), 0.f);
        h0a[1] = fmaxf(bf2f(xa.y) + bf2f(pa.y), 0.f);
        h0a[2] = fmaxf(bf2f(xa.z) + bf2f(pa.z), 0.f);
        h0a[3] = fmaxf(bf2f(xa.w) + bf2f(pa.w), 0.f);
        h0b[0] = fmaxf(bf2f(xb.x) + bf2f(pb.x), 0.f);
        h0b[1] = fmaxf(bf2f(xb.y) + bf2f(pb.y), 0.f);
        h0b[2] = fmaxf(bf2f(xb.z) + bf2f(pb.z), 0.f);
        h0b[3] = fmaxf(bf2f(xb.w) + bf2f(pb.w), 0.f);
        uint2 oa, ob;
        oa.x = fpack(fmaxf(bf2f(sa.x) - bf2f(wb.x) + h0a[0], 0.f),
                     fmaxf(bf2f(sa.y) - bf2f(wb.y) + h0a[1], 0.f));
        oa.y = fpack(fmaxf(bf2f(sa.z) - bf2f(wb.z) + h0a[2], 0.f),
                     fmaxf(bf2f(sa.w) - bf2f(wb.w) + h0a[3], 0.f));
        ob.x = fpack(fmaxf(bf2f(sb.x) - bf2f(wa.x) + h0b[0], 0.f),
                     fmaxf(bf2f(sb.y) - bf2f(wa.y) + h0b[1], 0.f));
        ob.y = fpack(fmaxf(bf2f(sb.z) - bf2f(wa.z) + h0b[2], 0.f),
                     fmaxf(bf2f(sb.w) - bf2f(wa.w) + h0b[3], 0.f));
        *(uint2*)&h[Ea * HP + c0] = oa;
        *(uint2*)&h[Eb * HP + c0] = ob;
    }
}

// K4: Sb[n][:] = bf16( bias[:] + segsum );  stride HID
__global__ __launch_bounds__(256) void gather_sum(
    const ushort_t* __restrict__ src, const int* __restrict__ offsets,
    const int* __restrict__ ends, const int* __restrict__ eid,
    const float* __restrict__ bias, ushort_t* __restrict__ Sb)
{
    long idx = (long)blockIdx.x * 256 + threadIdx.x;
    if (idx >= (long)N_NODES * 75) return;
    int n = (int)(idx / 75);
    int g = (int)(idx % 75);
    int beg = offsets[n], end = ends[n];
    float a0 = 0.f, a1 = 0.f, a2 = 0.f, a3 = 0.f;
    float b0 = 0.f, b1 = 0.f, b2 = 0.f, b3 = 0.f;
    int j = beg;
    for (; j + 1 < end; j += 2) {
        int e0i = eid[j], e1i = eid[j + 1];
        ushort4 v0 = ((const ushort4*)src)[(long)e0i * (HP / 4) + g];
        ushort4 v1 = ((const ushort4*)src)[(long)e1i * (HP / 4) + g];
        a0 += bf2f(v0.x); a1 += bf2f(v0.y); a2 += bf2f(v0.z); a3 += bf2f(v0.w);
        b0 += bf2f(v1.x); b1 += bf2f(v1.y); b2 += bf2f(v1.z); b3 += bf2f(v1.w);
    }
    if (j < end) {
        int e0i = eid[j];
        ushort4 v0 = ((const ushort4*)src)[(long)e0i * (HP / 4) + g];
        a0 += bf2f(v0.x); a1 += bf2f(v0.y); a2 += bf2f(v0.z); a3 += bf2f(v0.w);
    }
    float4 bv = *(const float4*)&bias[4 * g];
    uint2 o;
    o.x = fpack(a0 + b0 + bv.x, a1 + b1 + bv.y);
    o.y = fpack(a2 + b2 + bv.z, a3 + b3 + bv.w);
    *(uint2*)&Sb[(long)n * HID + 4 * g] = o;
}

// K4b: final gather -> bf16 into Ab cols 64..363
__global__ __launch_bounds__(256) void gather_ab(
    const ushort_t* __restrict__ src, const int* __restrict__ offsets,
    const int* __restrict__ ends, const int* __restrict__ eid,
    ushort_t* __restrict__ Ab)
{
    long idx = (long)blockIdx.x * 256 + threadIdx.x;
    if (idx >= (long)N_NODES * 75) return;
    int n = (int)(idx / 75);
    int g = (int)(idx % 75);
    int beg = offsets[n], end = ends[n];
    float a0 = 0.f, a1 = 0.f, a2 = 0.f, a3 = 0.f;
    float b0 = 0.f, b1 = 0.f, b2 = 0.f, b3 = 0.f;
    int j = beg;
    for (; j + 1 < end; j += 2) {
        int e0i = eid[j], e1i = eid[j + 1];
        ushort4 v0 = ((const ushort4*)src)[(long)e0i * (HP / 4) + g];
        ushort4 v1 = ((const ushort4*)src)[(long)e1i * (HP / 4) + g];
        a0 += bf2f(v0.x); a1 += bf2f(v0.y); a2 += bf2f(v0.z); a3 += bf2f(v0.w);
        b0 += bf2f(v1.x); b1 += bf2f(v1.y); b2 += bf2f(v1.z); b3 += bf2f(v1.w);
    }
    if (j < end) {
        int e0i = eid[j];
        ushort4 v0 = ((const ushort4*)src)[(long)e0i * (HP / 4) + g];
        a0 += bf2f(v0.x); a1 += bf2f(v0.y); a2 += bf2f(v0.z); a3 += bf2f(v0.w);
    }
    uint2 o;
    o.x = fpack(a0 + b0, a1 + b1);
    o.y = fpack(a2 + b2, a3 + b3);
    *(uint2*)&Ab[(long)n * KE2N + 64 + 4 * g] = o;
}

__global__ __launch_bounds__(256) void x_fill(
    const float* __restrict__ x, ushort_t* __restrict__ Ab)
{
    long idx = (long)blockIdx.x * 256 + threadIdx.x;
    if (idx >= (long)N_NODES * 21) return;
    int n = (int)(idx / 21);
    int q = (int)(idx % 21);
    if (q < 16) {
        float4 v = *(const float4*)&x[(long)n * 64 + 4 * q];
        uint2 o;
        o.x = fpack(v.x, v.y);
        o.y = fpack(v.z, v.w);
        *(uint2*)&Ab[(long)n * KE2N + 4 * q] = o;
    } else {
        uint2 o; o.x = 0; o.y = 0;
        *(uint2*)&Ab[(long)n * KE2N + 364 + 4 * (q - 16)] = o;
    }
}

// K7: hn = relu(Ab @ W_e2n + b)
__global__ __launch_bounds__(256) void e2n_mfma(
    const ushort_t* __restrict__ Ab, const ushort_t* __restrict__ wfrag2,
    const float* __restrict__ b_e2n, float* __restrict__ hn)
{
    const int tid = threadIdx.x;
    const int wave = tid >> 6, lane = tid & 63;
    const int quad = lane >> 4, m = lane & 15;
    const long n0 = (long)blockIdx.x * 64;
    const int nt0 = wave * 5;

    f32x4 acc[5][4];
    #pragma unroll
    for (int t = 0; t < 5; ++t)
        #pragma unroll
        for (int mt = 0; mt < 4; ++mt)
            acc[t][mt] = (f32x4){0.f, 0.f, 0.f, 0.f};

    for (int c = 0; c < 12; ++c) {
        short8 a[4];
        #pragma unroll
        for (int mt = 0; mt < 4; ++mt) {
            long r = n0 + mt * 16 + m;
            if (r > N_NODES - 1) r = N_NODES - 1;
            a[mt] = *(const short8*)(Ab + r * KE2N + c * 32 + quad * 8);
        }
        #pragma unroll
        for (int t = 0; t < 5; ++t) {
            short8 b = *(const short8*)(wfrag2
                + ((size_t)(c * NTILES + nt0 + t) * 64 + lane) * 8);
            #pragma unroll
            for (int mt = 0; mt < 4; ++mt)
                acc[t][mt] = __builtin_amdgcn_mfma_f32_16x16x32_bf16(
                    a[mt], b, acc[t][mt], 0, 0, 0);
        }
    }

    #pragma unroll
    for (int t = 0; t < 5; ++t) {
        int col = (nt0 + t) * 16 + m;
        if (col >= HID) continue;
        float bias = b_e2n[col];
        #pragma unroll
        for (int mt = 0; mt < 4; ++mt) {
            long rw = n0 + mt * 16 + quad * 4;
            #pragma unroll
            for (int r = 0; r < 4; ++r) {
                long rowi = rw + r;
                if (rowi < N_NODES)
                    hn[rowi * HP + col] = fmaxf(acc[t][mt][r] + bias, 0.f);
            }
        }
    }
}

__global__ __launch_bounds__(256) void pool_graph(
    const float* __restrict__ hn, const int* __restrict__ goff,
    float* __restrict__ pooled)
{
    int g = blockIdx.x;
    int beg = goff[g], end = goff[g + 1];
    for (int c = threadIdx.x; c < HID; c += 256) {
        float acc = 0.f;
        for (int n = beg; n < end; ++n)
            acc += hn[(long)n * HP + c];
        pooled[(long)g * HID + c] = acc;
    }
}

__global__ __launch_bounds__(64) void ffn_out(
    const float* __restrict__ pooled, const float* __restrict__ W_ffn,
    const float* __restrict__ b_ffn, float* __restrict__ out)
{
    int g = blockIdx.x;
    int lane = threadIdx.x;
    float s = 0.f;
    for (int c = lane; c < HID; c += 64)
        s += pooled[(long)g * HID + c] * W_ffn[c];
    #pragma unroll
    for (int off = 32; off > 0; off >>= 1)
        s += __shfl_down(s, off, 64);
    if (lane == 0) out[g] = s + b_ffn[0];
}

extern "C" void kernel_launch(void* const* d_in, const int* in_sizes, int n_in,
                              void* d_out, int out_size, void* d_ws, size_t ws_size,
                              hipStream_t stream) {
    const float* x         = (const float*)d_in[0];
    const float* edge_attr = (const float*)d_in[1];
    const int*   edge_index= (const int*)d_in[2];
    const int*   batch     = (const int*)d_in[3];
    const float* W_init    = (const float*)d_in[4];
    const float* b_init    = (const float*)d_in[5];
    const float* W_convs   = (const float*)d_in[6];
    const float* b_convs   = (const float*)d_in[7];
    const float* W_e2n     = (const float*)d_in[8];
    const float* b_e2n     = (const float*)d_in[9];
    const float* W_ffn     = (const float*)d_in[10];
    const float* b_ffn     = (const float*)d_in[11];
    float* out = (float*)d_out;

    const int* row = edge_index;
    const int* col = edge_index + N_EDGES;
    const float* W2 = W_init + (size_t)F_NODE * HID;

    // Workspace (~236 MB) — fits (ws known >= 255 MB from R12)
    const size_t need = (size_t)N_EDGES * HP * 2
                      + (size_t)N_NODES * HID * 2
                      + (size_t)N_NODES * KE2N * 2
                      + (size_t)N_GRAPHS * HID * 4
                      + (size_t)N_NODES * 4 * 2 + (size_t)N_EDGES * 4
                      + (size_t)DEPTH * WFRAG_USHORT_PER_LAYER * 2
                      + (size_t)WE2NFRAG_USHORT * 2
                      + (size_t)W2FRAG_USHORT * 2
                      + (size_t)(N_GRAPHS + 1 + N_GRAPHS) * 4 + 32768;
    if (ws_size < need) return;

    char* p = (char*)d_ws;
    auto take = [&](size_t bytes) {
        char* q = p;
        p += (bytes + 255) & ~(size_t)255;
        return q;
    };
    ushort_t* h       = (ushort_t*)take((size_t)N_EDGES * HP * 2);
    ushort_t* Sb      = (ushort_t*)take((size_t)N_NODES * HID * 2);
    ushort_t* Ab      = (ushort_t*)take((size_t)N_NODES * KE2N * 2);
    float*    pooled  = (float*)take((size_t)N_GRAPHS * HID * 4);
    int*      cursor  = (int*)take((size_t)N_NODES * 4);
    int*      offsets = (int*)take((size_t)N_NODES * 4);
    int*      eid     = (int*)take((size_t)N_EDGES * 4);
    ushort_t* wfrag   = (ushort_t*)take((size_t)DEPTH * WFRAG_USHORT_PER_LAYER * 2);
    ushort_t* wfrag2  = (ushort_t*)take((size_t)WE2NFRAG_USHORT * 2);
    ushort_t* w2frag  = (ushort_t*)take((size_t)W2FRAG_USHORT * 2);
    int*      gdeg    = (int*)take((size_t)N_GRAPHS * 4);
    int*      goff    = (int*)take((size_t)(N_GRAPHS + 1) * 4);

    ushort_t* xW1b = Ab;        // alias: xW1b dead before x_fill writes Ab
    float*    hn   = (float*)h; // alias: h dead after gather_ab

    // CSR + graph-offset build
    hipMemsetAsync(cursor, 0, (size_t)N_NODES * 4, stream);
    hipMemsetAsync(gdeg, 0, (size_t)N_GRAPHS * 4, stream);
    csr_hist<<<N_EDGES / 256, 256, 0, stream>>>(col, cursor);
    csr_scan<<<1, 256, 0, stream>>>(cursor, offsets, cursor);
    csr_fill<<<N_EDGES / 256, 256, 0, stream>>>(col, cursor, eid);
    ghist<<<(N_NODES + 255) / 256, 256, 0, stream>>>(batch, gdeg);
    gscan<<<1, 128, 0, stream>>>(gdeg, goff);

    wfrag_build<<<dim3(10, NTILES, DEPTH), 64, 0, stream>>>(W_convs, wfrag);
    wfrag2_build<<<dim3(12, NTILES, 1), 64, 0, stream>>>(W_e2n, wfrag2);
    w2frag_build<<<NTILES, 64, 0, stream>>>(W2, w2frag);

    node_init_gemm<<<N_NODES / 16, 256, 0, stream>>>(x, W_init, b_init, xW1b);

    const int GS_GRID = ((N_NODES * 75) + 255) / 256;

    // layer 0
    fused_conv<false><<<N_EDGES / 32, 256, 0, stream>>>(
        h, Sb, xW1b, edge_attr, row, w2frag, wfrag);
    gather_sum<<<GS_GRID, 256, 0, stream>>>(
        h, offsets, cursor, eid, b_convs + 0 * HID, Sb);
    // layers 1,2
    fused_conv<true><<<N_EDGES / 32, 256, 0, stream>>>(
        h, Sb, xW1b, edge_attr, row, w2frag,
        wfrag + 1 * (size_t)WFRAG_USHORT_PER_LAYER);
    gather_sum<<<GS_GRID, 256, 0, stream>>>(
        h, offsets, cursor, eid, b_convs + 1 * HID, Sb);
    fused_conv<true><<<N_EDGES / 32, 256, 0, stream>>>(
        h, Sb, xW1b, edge_attr, row, w2frag,
        wfrag + 2 * (size_t)WFRAG_USHORT_PER_LAYER);
    gather_sum<<<GS_GRID, 256, 0, stream>>>(
        h, offsets, cursor, eid, b_convs + 2 * HID, Sb);
    // final update
    edge_update_mfma<<<N_EDGES / 32, 256, 0, stream>>>(
        h, Sb, xW1b, edge_attr, row, w2frag);

    // ---- e2n path ----
    x_fill<<<((N_NODES * 21) + 255) / 256, 256, 0, stream>>>(x, Ab);
    gather_ab<<<GS_GRID, 256, 0, stream>>>(h, offsets, cursor, eid, Ab);
    e2n_mfma<<<(N_NODES + 63) / 64, 256, 0, stream>>>(Ab, wfrag2, b_e2n, hn);
    pool_graph<<<N_GRAPHS, 256, 0, stream>>>(hn, goff, pooled);
    ffn_out<<<N_GRAPHS, 64, 0, stream>>>(pooled, W_ffn, b_ffn, out);
}